// Round 2
// baseline (1719.135 us; speedup 1.0000x reference)
//
#include <hip/hip_runtime.h>

typedef unsigned short u16;
typedef unsigned int u32;
using bf16x8 = __attribute__((ext_vector_type(8))) short;
using f32x4  = __attribute__((ext_vector_type(4))) float;

#define EPS 1e-5f

__device__ __forceinline__ u16 f2bf(float f) {
    union { float f; u32 u; } v; v.f = f;
    u32 r = v.u + 0x7FFFu + ((v.u >> 16) & 1u);   // RNE
    return (u16)(r >> 16);
}
__device__ __forceinline__ float bf2f(u16 u) {
    union { u32 u; float f; } v; v.u = ((u32)u) << 16;
    return v.f;
}
__device__ __forceinline__ void gl16(const void* g, void* s) {
    __builtin_amdgcn_global_load_lds(
        (const __attribute__((address_space(1))) u32*)g,
        (__attribute__((address_space(3))) u32*)s, 16, 0, 0);
}
__device__ __forceinline__ float sigm(float x) { return 1.f / (1.f + __expf(-x)); }

// ---------------- fp32 -> bf16 convert (grid = n/4 units) ----------------
__global__ void conv_bf16(const float* __restrict__ src, u16* __restrict__ dst, int n4) {
    int i = blockIdx.x * 256 + threadIdx.x;
    if (i >= n4) return;
    float4 v = reinterpret_cast<const float4*>(src)[i];
    u32 lo = (u32)f2bf(v.x) | ((u32)f2bf(v.y) << 16);
    u32 hi = (u32)f2bf(v.z) | ((u32)f2bf(v.w) << 16);
    reinterpret_cast<uint2*>(dst)[i] = make_uint2(lo, hi);
}

// ---------------- RMSNorm: fp32 [4096,2048] -> bf16, grid = 4096 rows ----------------
__global__ void rmsnorm_k(const float* __restrict__ x, const float* __restrict__ wt,
                          u16* __restrict__ out) {
    __shared__ float red[4];
    const int row = blockIdx.x, t = threadIdx.x;
    const float* xr = x + (size_t)row * 2048;
    float4 v0 = *reinterpret_cast<const float4*>(&xr[t * 8]);
    float4 v1 = *reinterpret_cast<const float4*>(&xr[t * 8 + 4]);
    float ss = v0.x*v0.x + v0.y*v0.y + v0.z*v0.z + v0.w*v0.w
             + v1.x*v1.x + v1.y*v1.y + v1.z*v1.z + v1.w*v1.w;
#pragma unroll
    for (int d = 1; d < 64; d <<= 1) ss += __shfl_xor(ss, d);
    if ((t & 63) == 0) red[t >> 6] = ss;
    __syncthreads();
    const float tot = red[0] + red[1] + red[2] + red[3];
    const float s = 1.f / sqrtf(tot * (1.f / 2048.f) + EPS);
    float4 w0 = *reinterpret_cast<const float4*>(&wt[t * 8]);
    float4 w1 = *reinterpret_cast<const float4*>(&wt[t * 8 + 4]);
    u32 o[4];
    o[0] = (u32)f2bf(v0.x * s * w0.x) | ((u32)f2bf(v0.y * s * w0.y) << 16);
    o[1] = (u32)f2bf(v0.z * s * w0.z) | ((u32)f2bf(v0.w * s * w0.w) << 16);
    o[2] = (u32)f2bf(v1.x * s * w1.x) | ((u32)f2bf(v1.y * s * w1.y) << 16);
    o[3] = (u32)f2bf(v1.z * s * w1.z) | ((u32)f2bf(v1.w * s * w1.w) << 16);
    *reinterpret_cast<uint4*>(&out[(size_t)row * 2048 + t * 8]) =
        make_uint4(o[0], o[1], o[2], o[3]);
}

// ---------------- L2 norm of q/k rows in qkv buffer (in place) ----------------
// qkv: [4096, 6144] bf16; wave per (n, which(q/k), h); 2 elems/lane over DH=128
__global__ void qk_l2norm(u16* __restrict__ qkv) {
    const int wid = blockIdx.x * 4 + (threadIdx.x >> 6);
    const int l = threadIdx.x & 63;
    const int n = wid >> 5;
    const int rem = wid & 31;
    const int which = rem >> 4;   // 0=q, 1=k
    const int h = rem & 15;
    u16* p = qkv + (size_t)n * 6144 + which * 2048 + h * 128 + l * 2;
    u32 v = *reinterpret_cast<const u32*>(p);
    float f0 = bf2f((u16)(v & 0xffff)), f1 = bf2f((u16)(v >> 16));
    float ss = f0 * f0 + f1 * f1;
#pragma unroll
    for (int d = 1; d < 64; d <<= 1) ss += __shfl_xor(ss, d);
    const float sc = 1.f / fmaxf(sqrtf(ss), 1e-12f);
    *reinterpret_cast<u32*>(p) = (u32)f2bf(f0 * sc) | ((u32)f2bf(f1 * sc) << 16);
}

// ---------------- generic NT GEMM: C[M,N] = A[M,K](bf16) x B[N,K](bf16)^T ----------------
// 128x128 tile, 4 waves (2x2), BK=32, global_load_lds staging. EPI:
//  0: outB[row*ldc+col] = bf16(C)
//  1: outF = C (f32), outB = bf16(C)
//  2: g = sigmoid(C + bias[col]); outG = g*addend + (1-g)*resid   (fused gated residual)
template <int EPI>
__global__ void gemm_bt(const u16* __restrict__ A, const u16* __restrict__ B,
                        float* __restrict__ outF, u16* __restrict__ outB,
                        const float* __restrict__ bias, const float* __restrict__ addend,
                        const float* __restrict__ resid, float* __restrict__ outG,
                        int M, int N, int K, int ldc) {
    __shared__ u16 as_[128 * 32];
    __shared__ u16 bs_[128 * 32];
    const int t = threadIdx.x;
    const int bm = blockIdx.x, bn = blockIdx.y;
    const int w = t >> 6, l = t & 63;
    const int wr = w >> 1, wc = w & 1;
    const int lr = l & 15, lg = l >> 4;
    f32x4 acc[4][4];
#pragma unroll
    for (int i = 0; i < 4; i++)
#pragma unroll
        for (int j = 0; j < 4; j++) acc[i][j] = (f32x4){0.f, 0.f, 0.f, 0.f};

    const int r0 = t >> 2;
    const int c0 = (t & 3) << 3;
    const u16* aG = A + (size_t)(bm * 128 + r0) * K + c0;
    const u16* bG = B + (size_t)(bn * 128 + r0) * K + c0;
    const size_t step64 = (size_t)64 * K;
    u16* as0 = &as_[t * 8]; u16* as1 = &as_[2048 + t * 8];
    u16* bs0 = &bs_[t * 8]; u16* bs1 = &bs_[2048 + t * 8];

    for (int kt = 0; kt < K; kt += 32) {
        __syncthreads();
        gl16(aG + kt, as0);
        gl16(aG + step64 + kt, as1);
        gl16(bG + kt, bs0);
        gl16(bG + step64 + kt, bs1);
        __syncthreads();
        bf16x8 af[4], bf[4];
#pragma unroll
        for (int i = 0; i < 4; i++)
            af[i] = *reinterpret_cast<const bf16x8*>(&as_[(wr * 64 + i * 16 + lr) * 32 + lg * 8]);
#pragma unroll
        for (int j = 0; j < 4; j++)
            bf[j] = *reinterpret_cast<const bf16x8*>(&bs_[(wc * 64 + j * 16 + lr) * 32 + lg * 8]);
#pragma unroll
        for (int i = 0; i < 4; i++)
#pragma unroll
            for (int j = 0; j < 4; j++)
                acc[i][j] = __builtin_amdgcn_mfma_f32_16x16x32_bf16(af[i], bf[j], acc[i][j], 0, 0, 0);
    }
#pragma unroll
    for (int i = 0; i < 4; i++) {
        const int row = bm * 128 + wr * 64 + i * 16 + lg * 4;
#pragma unroll
        for (int j = 0; j < 4; j++) {
            const int col = bn * 128 + wc * 64 + j * 16 + lr;
#pragma unroll
            for (int q = 0; q < 4; q++) {
                const size_t idx = (size_t)(row + q) * ldc + col;
                const float v = acc[i][j][q];
                if (EPI == 0) {
                    outB[idx] = f2bf(v);
                } else if (EPI == 1) {
                    outF[idx] = v;
                    outB[idx] = f2bf(v);
                } else {
                    const float g = sigm(v + bias[col]);
                    outG[idx] = g * addend[idx] + (1.f - g) * resid[idx];
                }
            }
        }
    }
}

// ---------------- causal flash attention ----------------
// qkv: [4096, 6144] bf16 (cols 0..2047 q(norm), 2048.. k(norm), 4096.. v)
// grid (S/64=32, B*H=32), 4 waves x 16 q-rows. out: [4096, 2048] bf16.
__global__ void flash_attn(const u16* __restrict__ qkv, const float* __restrict__ temp,
                           u16* __restrict__ out) {
    __shared__ u16 klds[64 * 128];
    __shared__ u16 vlds[128 * 64];   // V^T
    __shared__ u16 plds[4][16 * 64];
    const int t = threadIdx.x, w = t >> 6, l = t & 63;
    const int lr = l & 15, lg = l >> 4;
    const int qt = blockIdx.x;
    const int b = blockIdx.y >> 4, h = blockIdx.y & 15;
    const size_t base = (size_t)b * 2048;
    const float tmp = temp[h];
    const int qrow = qt * 64 + w * 16 + lr;      // A-frag rows (within batch)
    const int qr0 = qt * 64 + w * 16 + lg * 4;   // C rows base
    bf16x8 qf[4];
#pragma unroll
    for (int kk = 0; kk < 4; kk++)
        qf[kk] = *reinterpret_cast<const bf16x8*>(
            &qkv[(base + qrow) * 6144 + h * 128 + kk * 32 + lg * 8]);
    f32x4 o[8];
#pragma unroll
    for (int i = 0; i < 8; i++) o[i] = (f32x4){0.f, 0.f, 0.f, 0.f};
    float m[4] = {-1e30f, -1e30f, -1e30f, -1e30f};
    float ls[4] = {0.f, 0.f, 0.f, 0.f};

    for (int kt = 0; kt <= qt; ++kt) {
        __syncthreads();
#pragma unroll
        for (int j2 = 0; j2 < 4; j2++) {
            const int e = j2 * 256 + t;
            const int r = e >> 4;
            const int c = (e & 15) << 3;
            const size_t grow = (base + kt * 64 + r) * 6144 + h * 128 + c;
            uint4 kq = *reinterpret_cast<const uint4*>(&qkv[grow + 2048]);
            *reinterpret_cast<uint4*>((char*)klds + ((r * 256 + c * 2) ^ ((r & 7) << 4))) = kq;
            union { uint4 u; u16 s[8]; } vv;
            vv.u = *reinterpret_cast<const uint4*>(&qkv[grow + 4096]);
#pragma unroll
            for (int jj = 0; jj < 8; jj++) {
                const int dh = c + jj;
                *reinterpret_cast<u16*>((char*)vlds + ((dh * 128 + r * 2) ^ ((dh & 7) << 4))) = vv.s[jj];
            }
        }
        __syncthreads();
        // S = Q K^T  (16 x 64 per wave)
        f32x4 s[4];
#pragma unroll
        for (int nf = 0; nf < 4; nf++) {
            f32x4 a = (f32x4){0.f, 0.f, 0.f, 0.f};
            const int kv = nf * 16 + lr;
#pragma unroll
            for (int kk = 0; kk < 4; kk++) {
                bf16x8 kf = *reinterpret_cast<const bf16x8*>(
                    (char*)klds + ((kv * 256 + kk * 64 + lg * 16) ^ ((kv & 7) << 4)));
                a = __builtin_amdgcn_mfma_f32_16x16x32_bf16(qf[kk], kf, a, 0, 0, 0);
            }
            s[nf] = a;
        }
        // temp scale + causal mask + online softmax
        float mx[4] = {-1e30f, -1e30f, -1e30f, -1e30f};
#pragma unroll
        for (int nf = 0; nf < 4; nf++) {
            const int kvi = kt * 64 + nf * 16 + lr;
#pragma unroll
            for (int q = 0; q < 4; q++) {
                float sv = (kvi <= qr0 + q) ? s[nf][q] * tmp : -1e30f;
                s[nf][q] = sv;
                mx[q] = fmaxf(mx[q], sv);
            }
        }
#pragma unroll
        for (int q = 0; q < 4; q++) {
#pragma unroll
            for (int d = 1; d < 16; d <<= 1) mx[q] = fmaxf(mx[q], __shfl_xor(mx[q], d));
        }
        float fac[4], rs[4];
#pragma unroll
        for (int q = 0; q < 4; q++) {
            const float mn = fmaxf(m[q], mx[q]);
            fac[q] = __expf(m[q] - mn);
            m[q] = mn;
            rs[q] = 0.f;
        }
#pragma unroll
        for (int nf = 0; nf < 4; nf++) {
#pragma unroll
            for (int q = 0; q < 4; q++) {
                const float p = __expf(s[nf][q] - m[q]);
                s[nf][q] = p;
                rs[q] += p;
            }
        }
        // P -> LDS (swizzled) for A-operand relayout
#pragma unroll
        for (int nf = 0; nf < 4; nf++) {
            const int col = nf * 16 + lr;
#pragma unroll
            for (int q = 0; q < 4; q++) {
                const int row = lg * 4 + q;
                *reinterpret_cast<u16*>((char*)&plds[w][0] +
                    ((row * 128 + col * 2) ^ ((row & 7) << 4))) = f2bf(s[nf][q]);
            }
        }
#pragma unroll
        for (int q = 0; q < 4; q++) {
#pragma unroll
            for (int d = 1; d < 16; d <<= 1) rs[q] += __shfl_xor(rs[q], d);
            ls[q] = ls[q] * fac[q] + rs[q];
        }
#pragma unroll
        for (int nf2 = 0; nf2 < 8; nf2++)
#pragma unroll
            for (int q = 0; q < 4; q++) o[nf2][q] *= fac[q];
        // O += P V
#pragma unroll
        for (int ks = 0; ks < 2; ks++) {
            bf16x8 pf = *reinterpret_cast<const bf16x8*>((char*)&plds[w][0] +
                ((lr * 128 + ks * 64 + lg * 16) ^ ((lr & 7) << 4)));
#pragma unroll
            for (int nf2 = 0; nf2 < 8; nf2++) {
                const int dh = nf2 * 16 + lr;
                bf16x8 vf = *reinterpret_cast<const bf16x8*>((char*)vlds +
                    ((dh * 128 + ks * 64 + lg * 16) ^ ((dh & 7) << 4)));
                o[nf2] = __builtin_amdgcn_mfma_f32_16x16x32_bf16(pf, vf, o[nf2], 0, 0, 0);
            }
        }
    }
#pragma unroll
    for (int nf2 = 0; nf2 < 8; nf2++) {
        const int col = h * 128 + nf2 * 16 + lr;
#pragma unroll
        for (int q = 0; q < 4; q++) {
            const float v = o[nf2][q] / ls[q];
            out[(base + qr0 + q) * 2048 + col] = f2bf(v);
        }
    }
}

// ---------------- SwiGLU combine (one HFF quarter) ----------------
// f3q: [4096, 6144] bf16 (gateQ | upQ | gate2Q, 2048 each)
// comb: pre-offset pointer into combo [4096, 8192] at column quarter*2048
__global__ void swiglu_comb(const u16* __restrict__ f3, u16* __restrict__ comb) {
    const size_t u = (size_t)blockIdx.x * 256 + threadIdx.x;  // 8-elem units of [4096,2048]
    const size_t n = u >> 8;              // 256 units per row
    const int f = (int)(u & 255) << 3;
    const u16* gp = f3 + n * 6144 + f;
    union { uint4 q; u16 s[8]; } g, up, g2;
    g.q  = *reinterpret_cast<const uint4*>(gp);
    up.q = *reinterpret_cast<const uint4*>(gp + 2048);
    g2.q = *reinterpret_cast<const uint4*>(gp + 4096);
    u32 r[4];
#pragma unroll
    for (int i = 0; i < 4; i++) {
        float a0 = bf2f(g.s[2 * i]),     a1 = bf2f(g.s[2 * i + 1]);
        float b0 = bf2f(up.s[2 * i]),    b1 = bf2f(up.s[2 * i + 1]);
        float c0 = bf2f(g2.s[2 * i]),    c1 = bf2f(g2.s[2 * i + 1]);
        float r0 = a0 * sigm(a0) * b0 * sigm(c0);
        float r1 = a1 * sigm(a1) * b1 * sigm(c1);
        r[i] = (u32)f2bf(r0) | ((u32)f2bf(r1) << 16);
    }
    *reinterpret_cast<uint4*>(comb + n * 8192 + f) = make_uint4(r[0], r[1], r[2], r[3]);
}

// ---------------- launch ----------------
extern "C" void kernel_launch(void* const* d_in, const int* in_sizes, int n_in,
                              void* d_out, int out_size, void* d_ws, size_t ws_size,
                              hipStream_t stream) {
    const float* x      = (const float*)d_in[0];
    const float* q_w    = (const float*)d_in[1];
    const float* k_w    = (const float*)d_in[2];
    const float* v_w    = (const float*)d_in[3];
    const float* o_w    = (const float*)d_in[4];
    const float* temp   = (const float*)d_in[5];
    const float* ln1_w  = (const float*)d_in[6];
    const float* ln2_w  = (const float*)d_in[7];
    const float* gate_w = (const float*)d_in[8];
    const float* up_w   = (const float*)d_in[9];
    const float* gate2_w= (const float*)d_in[10];
    const float* down_w = (const float*)d_in[11];
    const float* ag_w   = (const float*)d_in[12];
    const float* ag_b   = (const float*)d_in[13];
    const float* fg_w   = (const float*)d_in[14];
    const float* fg_b   = (const float*)d_in[15];

    // ---- workspace regions (peak 251,658,240 B; lifetimes disjoint) ----
    char* ws = (char*)d_ws;
    u16*  Wbuf = (u16*)(ws);                      // 33,554,432 B  weight scratch (serial reuse)
    u16*  hbuf = (u16*)(ws + 33554432);           // 16,777,216 B  rmsnorm output
    float* x1  = (float*)(ws + 50331648);         // 33,554,432 B  post-attn residual (f32)
    u16*  combo= (u16*)(ws + 83886080);           // 67,108,864 B  [4096,8192] bf16
    char* E    = ws + 150994944;                  // 50,331,648 B  qkvact -> aof/aob -> ffn3q
    char* F    = ws + 201326592;                  // 33,554,432 B  attnb -> fff
    u16*  ffb  = (u16*)(ws + 234881024);          // 16,777,216 B

    u16*   qkvact = (u16*)E;                      // [4096,6144] bf16
    float* aof    = (float*)E;                    // [4096,2048] f32
    u16*   aob    = (u16*)(E + 33554432);         // [4096,2048] bf16
    u16*   ffn3q  = (u16*)E;                      // [4096,6144] bf16 (per quarter)
    u16*   attnb  = (u16*)F;                      // [4096,2048] bf16
    float* fff    = (float*)F;                    // [4096,2048] f32

    float* outp = (float*)d_out;
    const size_t DD = 2048ull * 2048ull;
    const int cg_d = (int)(DD / 4) / 256;         // 4096 blocks for a DxD weight

    // 1) h = rmsnorm(x, ln1)
    hipLaunchKernelGGL(rmsnorm_k, dim3(4096), dim3(256), 0, stream, x, ln1_w, hbuf);

    // 2) q/k/v projections -> qkvact slices (conv weight, then GEMM; serial reuse of Wbuf)
    const float* qkvw[3] = { q_w, k_w, v_w };
    for (int i = 0; i < 3; i++) {
        hipLaunchKernelGGL(conv_bf16, dim3(cg_d), dim3(256), 0, stream, qkvw[i], Wbuf, (int)(DD / 4));
        hipLaunchKernelGGL((gemm_bt<0>), dim3(32, 16), dim3(256), 0, stream,
                           hbuf, Wbuf, (float*)nullptr, qkvact + i * 2048,
                           (const float*)nullptr, (const float*)nullptr, (const float*)nullptr,
                           (float*)nullptr, 4096, 2048, 2048, 6144);
    }

    // 3) l2-normalize q,k in place
    hipLaunchKernelGGL(qk_l2norm, dim3(32768), dim3(256), 0, stream, qkvact);

    // 4) attention -> attnb (region F)
    hipLaunchKernelGGL(flash_attn, dim3(32, 32), dim3(256), 0, stream, qkvact, temp, attnb);

    // 5) attn_out = attn @ Wo^T  (f32 aof + bf16 aob, both in region E; qkvact dead)
    hipLaunchKernelGGL(conv_bf16, dim3(cg_d), dim3(256), 0, stream, o_w, Wbuf, (int)(DD / 4));
    hipLaunchKernelGGL((gemm_bt<1>), dim3(32, 16), dim3(256), 0, stream,
                       attnb, Wbuf, aof, aob,
                       (const float*)nullptr, (const float*)nullptr, (const float*)nullptr,
                       (float*)nullptr, 4096, 2048, 2048, 2048);

    // 6) x1 = sigmoid(attn_out@Wag^T + b)*attn_out + (1-g)*x
    hipLaunchKernelGGL(conv_bf16, dim3(cg_d), dim3(256), 0, stream, ag_w, Wbuf, (int)(DD / 4));
    hipLaunchKernelGGL((gemm_bt<2>), dim3(32, 16), dim3(256), 0, stream,
                       aob, Wbuf, (float*)nullptr, (u16*)nullptr,
                       ag_b, aof, x, x1, 4096, 2048, 2048, 2048);

    // 7) h2 = rmsnorm(x1, ln2)
    hipLaunchKernelGGL(rmsnorm_k, dim3(4096), dim3(256), 0, stream, x1, ln2_w, hbuf);

    // 8) FFN in 4 HFF quarters: conv (gate|up|gate2 quarter) -> GEMM -> swiglu into combo
    for (int qd = 0; qd < 4; qd++) {
        const size_t wofs = (size_t)qd * 2048 * 2048;
        hipLaunchKernelGGL(conv_bf16, dim3(cg_d), dim3(256), 0, stream, gate_w + wofs,  Wbuf,                 (int)(DD / 4));
        hipLaunchKernelGGL(conv_bf16, dim3(cg_d), dim3(256), 0, stream, up_w + wofs,    Wbuf + 2048 * 2048,   (int)(DD / 4));
        hipLaunchKernelGGL(conv_bf16, dim3(cg_d), dim3(256), 0, stream, gate2_w + wofs, Wbuf + 2 * 2048 * 2048, (int)(DD / 4));
        hipLaunchKernelGGL((gemm_bt<0>), dim3(32, 48), dim3(256), 0, stream,
                           hbuf, Wbuf, (float*)nullptr, ffn3q,
                           (const float*)nullptr, (const float*)nullptr, (const float*)nullptr,
                           (float*)nullptr, 4096, 6144, 2048, 6144);
        hipLaunchKernelGGL(swiglu_comb, dim3(4096), dim3(256), 0, stream, ffn3q, combo + qd * 2048);
    }

    // 9) ffn_out = combo @ Wdn^T (f32 fff + bf16 ffb)
    hipLaunchKernelGGL(conv_bf16, dim3(16384), dim3(256), 0, stream, down_w, Wbuf, (int)(2048ull * 8192 / 4));
    hipLaunchKernelGGL((gemm_bt<1>), dim3(32, 16), dim3(256), 0, stream,
                       combo, Wbuf, fff, ffb,
                       (const float*)nullptr, (const float*)nullptr, (const float*)nullptr,
                       (float*)nullptr, 4096, 2048, 8192, 2048);

    // 10) out = sigmoid(ffn_out@Wfg^T + b)*ffn_out + (1-g)*x1
    hipLaunchKernelGGL(conv_bf16, dim3(cg_d), dim3(256), 0, stream, fg_w, Wbuf, (int)(DD / 4));
    hipLaunchKernelGGL((gemm_bt<2>), dim3(32, 16), dim3(256), 0, stream,
                       ffb, Wbuf, (float*)nullptr, (u16*)nullptr,
                       fg_b, fff, x1, outp, 4096, 2048, 2048, 2048);
}

// Round 3
// 1652.823 us; speedup vs baseline: 1.0401x; 1.0401x over previous
//
#include <hip/hip_runtime.h>

typedef unsigned short u16;
typedef unsigned int u32;
using bf16x8 = __attribute__((ext_vector_type(8))) short;
using f32x4  = __attribute__((ext_vector_type(4))) float;

#define EPS 1e-5f

__device__ __forceinline__ u16 f2bf(float f) {
    union { float f; u32 u; } v; v.f = f;
    u32 r = v.u + 0x7FFFu + ((v.u >> 16) & 1u);   // RNE
    return (u16)(r >> 16);
}
__device__ __forceinline__ float bf2f(u16 u) {
    union { u32 u; float f; } v; v.u = ((u32)u) << 16;
    return v.f;
}
__device__ __forceinline__ void gl16(const void* g, void* s) {
    __builtin_amdgcn_global_load_lds(
        (const __attribute__((address_space(1))) u32*)g,
        (__attribute__((address_space(3))) u32*)s, 16, 0, 0);
}
__device__ __forceinline__ float sigm(float x) { return 1.f / (1.f + __expf(-x)); }

// ---------------- fp32 -> bf16 convert (grid = n/4 units) ----------------
__global__ void conv_bf16(const float* __restrict__ src, u16* __restrict__ dst, int n4) {
    int i = blockIdx.x * 256 + threadIdx.x;
    if (i >= n4) return;
    float4 v = reinterpret_cast<const float4*>(src)[i];
    u32 lo = (u32)f2bf(v.x) | ((u32)f2bf(v.y) << 16);
    u32 hi = (u32)f2bf(v.z) | ((u32)f2bf(v.w) << 16);
    reinterpret_cast<uint2*>(dst)[i] = make_uint2(lo, hi);
}

// ---------------- RMSNorm: fp32 [4096,2048] -> bf16, grid = 4096 rows ----------------
__global__ void rmsnorm_k(const float* __restrict__ x, const float* __restrict__ wt,
                          u16* __restrict__ out) {
    __shared__ float red[4];
    const int row = blockIdx.x, t = threadIdx.x;
    const float* xr = x + (size_t)row * 2048;
    float4 v0 = *reinterpret_cast<const float4*>(&xr[t * 8]);
    float4 v1 = *reinterpret_cast<const float4*>(&xr[t * 8 + 4]);
    float ss = v0.x*v0.x + v0.y*v0.y + v0.z*v0.z + v0.w*v0.w
             + v1.x*v1.x + v1.y*v1.y + v1.z*v1.z + v1.w*v1.w;
#pragma unroll
    for (int d = 1; d < 64; d <<= 1) ss += __shfl_xor(ss, d);
    if ((t & 63) == 0) red[t >> 6] = ss;
    __syncthreads();
    const float tot = red[0] + red[1] + red[2] + red[3];
    const float s = 1.f / sqrtf(tot * (1.f / 2048.f) + EPS);
    float4 w0 = *reinterpret_cast<const float4*>(&wt[t * 8]);
    float4 w1 = *reinterpret_cast<const float4*>(&wt[t * 8 + 4]);
    u32 o[4];
    o[0] = (u32)f2bf(v0.x * s * w0.x) | ((u32)f2bf(v0.y * s * w0.y) << 16);
    o[1] = (u32)f2bf(v0.z * s * w0.z) | ((u32)f2bf(v0.w * s * w0.w) << 16);
    o[2] = (u32)f2bf(v1.x * s * w1.x) | ((u32)f2bf(v1.y * s * w1.y) << 16);
    o[3] = (u32)f2bf(v1.z * s * w1.z) | ((u32)f2bf(v1.w * s * w1.w) << 16);
    *reinterpret_cast<uint4*>(&out[(size_t)row * 2048 + t * 8]) =
        make_uint4(o[0], o[1], o[2], o[3]);
}

// ---------------- L2 norm of q/k rows (in place); q additionally scaled by temp[h] ----------------
// qkv: [4096, 6144] bf16; wave per (n, which(q/k), h); 2 elems/lane over DH=128
__global__ void qk_l2norm(u16* __restrict__ qkv, const float* __restrict__ temp) {
    const int wid = blockIdx.x * 4 + (threadIdx.x >> 6);
    const int l = threadIdx.x & 63;
    const int n = wid >> 5;
    const int rem = wid & 31;
    const int which = rem >> 4;   // 0=q, 1=k
    const int h = rem & 15;
    u16* p = qkv + (size_t)n * 6144 + which * 2048 + h * 128 + l * 2;
    u32 v = *reinterpret_cast<const u32*>(p);
    float f0 = bf2f((u16)(v & 0xffff)), f1 = bf2f((u16)(v >> 16));
    float ss = f0 * f0 + f1 * f1;
#pragma unroll
    for (int d = 1; d < 64; d <<= 1) ss += __shfl_xor(ss, d);
    float sc = 1.f / fmaxf(sqrtf(ss), 1e-12f);
    if (which == 0) sc *= temp[h];          // fold per-head temperature into q
    *reinterpret_cast<u32*>(p) = (u32)f2bf(f0 * sc) | ((u32)f2bf(f1 * sc) << 16);
}

// ---------------- generic NT GEMM: C[M,N] = A[M,K](bf16) x B[N,K](bf16)^T ----------------
template <int EPI>
__global__ void gemm_bt(const u16* __restrict__ A, const u16* __restrict__ B,
                        float* __restrict__ outF, u16* __restrict__ outB,
                        const float* __restrict__ bias, const float* __restrict__ addend,
                        const float* __restrict__ resid, float* __restrict__ outG,
                        int M, int N, int K, int ldc) {
    __shared__ u16 as_[128 * 32];
    __shared__ u16 bs_[128 * 32];
    const int t = threadIdx.x;
    const int bm = blockIdx.x, bn = blockIdx.y;
    const int w = t >> 6, l = t & 63;
    const int wr = w >> 1, wc = w & 1;
    const int lr = l & 15, lg = l >> 4;
    f32x4 acc[4][4];
#pragma unroll
    for (int i = 0; i < 4; i++)
#pragma unroll
        for (int j = 0; j < 4; j++) acc[i][j] = (f32x4){0.f, 0.f, 0.f, 0.f};

    const int r0 = t >> 2;
    const int c0 = (t & 3) << 3;
    const u16* aG = A + (size_t)(bm * 128 + r0) * K + c0;
    const u16* bG = B + (size_t)(bn * 128 + r0) * K + c0;
    const size_t step64 = (size_t)64 * K;
    u16* as0 = &as_[t * 8]; u16* as1 = &as_[2048 + t * 8];
    u16* bs0 = &bs_[t * 8]; u16* bs1 = &bs_[2048 + t * 8];

    for (int kt = 0; kt < K; kt += 32) {
        __syncthreads();
        gl16(aG + kt, as0);
        gl16(aG + step64 + kt, as1);
        gl16(bG + kt, bs0);
        gl16(bG + step64 + kt, bs1);
        __syncthreads();
        bf16x8 af[4], bf[4];
#pragma unroll
        for (int i = 0; i < 4; i++)
            af[i] = *reinterpret_cast<const bf16x8*>(&as_[(wr * 64 + i * 16 + lr) * 32 + lg * 8]);
#pragma unroll
        for (int j = 0; j < 4; j++)
            bf[j] = *reinterpret_cast<const bf16x8*>(&bs_[(wc * 64 + j * 16 + lr) * 32 + lg * 8]);
#pragma unroll
        for (int i = 0; i < 4; i++)
#pragma unroll
            for (int j = 0; j < 4; j++)
                acc[i][j] = __builtin_amdgcn_mfma_f32_16x16x32_bf16(af[i], bf[j], acc[i][j], 0, 0, 0);
    }
#pragma unroll
    for (int i = 0; i < 4; i++) {
        const int row = bm * 128 + wr * 64 + i * 16 + lg * 4;
#pragma unroll
        for (int j = 0; j < 4; j++) {
            const int col = bn * 128 + wc * 64 + j * 16 + lr;
#pragma unroll
            for (int q = 0; q < 4; q++) {
                const size_t idx = (size_t)(row + q) * ldc + col;
                const float v = acc[i][j][q];
                if (EPI == 0) {
                    outB[idx] = f2bf(v);
                } else if (EPI == 1) {
                    outF[idx] = v;
                    outB[idx] = f2bf(v);
                } else {
                    const float g = sigm(v + bias[col]);
                    outG[idx] = g * addend[idx] + (1.f - g) * resid[idx];
                }
            }
        }
    }
}

// ---------------- causal flash attention (balanced + XCD-local) ----------------
// qkv: [4096, 6144] bf16 (q pre-scaled by temp & l2-normed, k l2-normed, v raw)
// grid: 512 blocks x 256 thr. Block handles q-tiles p and 31-p of one (b,h);
// mapping keeps all 16 blocks of a head on one XCD (round-robin heuristic).
#define VSWZ(dh) (((((dh) >> 3) ^ (dh)) & 7) << 4)
__global__ void flash_attn(const u16* __restrict__ qkv, u16* __restrict__ out) {
    __shared__ u16 klds[64 * 128];
    __shared__ u16 vlds[128 * 64];   // V^T, swizzled
    __shared__ u16 plds[4][16 * 64];
    const int t = threadIdx.x, w = t >> 6, l = t & 63;
    const int lr = l & 15, lg = l >> 4;
    const int b0 = blockIdx.x;
    const int xcd = b0 & 7, i0 = b0 >> 3;
    const int bh = ((i0 & 3) << 3) | xcd;      // all 16 blocks of a head share b0&7
    const int p = i0 >> 2;                     // 0..15
    const int b = bh >> 4, h = bh & 15;
    const size_t base = (size_t)b * 2048;

    for (int phase = 0; phase < 2; ++phase) {
        const int qt = phase ? (31 - p) : p;
        const int qrow = qt * 64 + w * 16 + lr;      // A-frag rows
        const int qr0 = qt * 64 + w * 16 + lg * 4;   // C rows base
        bf16x8 qf[4];
#pragma unroll
        for (int kk = 0; kk < 4; kk++)
            qf[kk] = *reinterpret_cast<const bf16x8*>(
                &qkv[(base + qrow) * 6144 + h * 128 + kk * 32 + lg * 8]);
        f32x4 o[8];
#pragma unroll
        for (int i = 0; i < 8; i++) o[i] = (f32x4){0.f, 0.f, 0.f, 0.f};
        float m[4] = {-1e30f, -1e30f, -1e30f, -1e30f};
        float ls[4] = {0.f, 0.f, 0.f, 0.f};

        for (int kt = 0; kt <= qt; ++kt) {
            __syncthreads();
#pragma unroll
            for (int j2 = 0; j2 < 4; j2++) {
                const int e = j2 * 256 + t;
                const int r = e >> 4;
                const int c = (e & 15) << 3;
                const size_t grow = (base + kt * 64 + r) * 6144 + h * 128 + c;
                uint4 kq = *reinterpret_cast<const uint4*>(&qkv[grow + 2048]);
                *reinterpret_cast<uint4*>((char*)klds + ((r * 256 + c * 2) ^ ((r & 7) << 4))) = kq;
                union { uint4 u; u16 s[8]; } vv;
                vv.u = *reinterpret_cast<const uint4*>(&qkv[grow + 4096]);
#pragma unroll
                for (int jj = 0; jj < 8; jj++) {
                    const int dh = c + jj;
                    *reinterpret_cast<u16*>((char*)vlds + ((dh * 128 + r * 2) ^ VSWZ(dh))) = vv.s[jj];
                }
            }
            __syncthreads();
            // S = Q K^T  (16 x 64 per wave)
            f32x4 s[4];
#pragma unroll
            for (int nf = 0; nf < 4; nf++) {
                f32x4 a = (f32x4){0.f, 0.f, 0.f, 0.f};
                const int kv = nf * 16 + lr;
#pragma unroll
                for (int kk = 0; kk < 4; kk++) {
                    bf16x8 kf = *reinterpret_cast<const bf16x8*>(
                        (char*)klds + ((kv * 256 + kk * 64 + lg * 16) ^ ((kv & 7) << 4)));
                    a = __builtin_amdgcn_mfma_f32_16x16x32_bf16(qf[kk], kf, a, 0, 0, 0);
                }
                s[nf] = a;
            }
            // causal mask only on the diagonal tile
            if (kt == qt) {
#pragma unroll
                for (int nf = 0; nf < 4; nf++) {
                    const int kvi = kt * 64 + nf * 16 + lr;
#pragma unroll
                    for (int q = 0; q < 4; q++)
                        if (kvi > qr0 + q) s[nf][q] = -1e30f;
                }
            }
            // online softmax
            float mx[4] = {-1e30f, -1e30f, -1e30f, -1e30f};
#pragma unroll
            for (int nf = 0; nf < 4; nf++)
#pragma unroll
                for (int q = 0; q < 4; q++) mx[q] = fmaxf(mx[q], s[nf][q]);
#pragma unroll
            for (int q = 0; q < 4; q++) {
#pragma unroll
                for (int d = 1; d < 16; d <<= 1) mx[q] = fmaxf(mx[q], __shfl_xor(mx[q], d));
            }
            float fac[4], rs[4];
#pragma unroll
            for (int q = 0; q < 4; q++) {
                const float mn = fmaxf(m[q], mx[q]);
                fac[q] = __expf(m[q] - mn);
                m[q] = mn;
                rs[q] = 0.f;
            }
#pragma unroll
            for (int nf = 0; nf < 4; nf++) {
#pragma unroll
                for (int q = 0; q < 4; q++) {
                    const float pv = __expf(s[nf][q] - m[q]);
                    s[nf][q] = pv;
                    rs[q] += pv;
                }
            }
            // P -> LDS (swizzled) for A-operand relayout
#pragma unroll
            for (int nf = 0; nf < 4; nf++) {
                const int col = nf * 16 + lr;
#pragma unroll
                for (int q = 0; q < 4; q++) {
                    const int row = lg * 4 + q;
                    *reinterpret_cast<u16*>((char*)&plds[w][0] +
                        ((row * 128 + col * 2) ^ ((row & 7) << 4))) = f2bf(s[nf][q]);
                }
            }
#pragma unroll
            for (int q = 0; q < 4; q++) {
#pragma unroll
                for (int d = 1; d < 16; d <<= 1) rs[q] += __shfl_xor(rs[q], d);
                ls[q] = ls[q] * fac[q] + rs[q];
            }
#pragma unroll
            for (int nf2 = 0; nf2 < 8; nf2++)
#pragma unroll
                for (int q = 0; q < 4; q++) o[nf2][q] *= fac[q];
            // O += P V
#pragma unroll
            for (int ks = 0; ks < 2; ks++) {
                bf16x8 pf = *reinterpret_cast<const bf16x8*>((char*)&plds[w][0] +
                    ((lr * 128 + ks * 64 + lg * 16) ^ ((lr & 7) << 4)));
#pragma unroll
                for (int nf2 = 0; nf2 < 8; nf2++) {
                    const int dh = nf2 * 16 + lr;
                    bf16x8 vf = *reinterpret_cast<const bf16x8*>((char*)vlds +
                        ((dh * 128 + ks * 64 + lg * 16) ^ VSWZ(dh)));
                    o[nf2] = __builtin_amdgcn_mfma_f32_16x16x32_bf16(pf, vf, o[nf2], 0, 0, 0);
                }
            }
        }
#pragma unroll
        for (int nf2 = 0; nf2 < 8; nf2++) {
            const int col = h * 128 + nf2 * 16 + lr;
#pragma unroll
            for (int q = 0; q < 4; q++) {
                const float v = o[nf2][q] / ls[q];
                out[(base + qr0 + q) * 2048 + col] = f2bf(v);
            }
        }
        __syncthreads();
    }
}

// ---------------- SwiGLU combine (one HFF quarter) ----------------
__global__ void swiglu_comb(const u16* __restrict__ f3, u16* __restrict__ comb) {
    const size_t u = (size_t)blockIdx.x * 256 + threadIdx.x;  // 8-elem units of [4096,2048]
    const size_t n = u >> 8;
    const int f = (int)(u & 255) << 3;
    const u16* gp = f3 + n * 6144 + f;
    union { uint4 q; u16 s[8]; } g, up, g2;
    g.q  = *reinterpret_cast<const uint4*>(gp);
    up.q = *reinterpret_cast<const uint4*>(gp + 2048);
    g2.q = *reinterpret_cast<const uint4*>(gp + 4096);
    u32 r[4];
#pragma unroll
    for (int i = 0; i < 4; i++) {
        float a0 = bf2f(g.s[2 * i]),     a1 = bf2f(g.s[2 * i + 1]);
        float b0 = bf2f(up.s[2 * i]),    b1 = bf2f(up.s[2 * i + 1]);
        float c0 = bf2f(g2.s[2 * i]),    c1 = bf2f(g2.s[2 * i + 1]);
        float r0 = a0 * sigm(a0) * b0 * sigm(c0);
        float r1 = a1 * sigm(a1) * b1 * sigm(c1);
        r[i] = (u32)f2bf(r0) | ((u32)f2bf(r1) << 16);
    }
    *reinterpret_cast<uint4*>(comb + n * 8192 + f) = make_uint4(r[0], r[1], r[2], r[3]);
}

// ---------------- launch ----------------
extern "C" void kernel_launch(void* const* d_in, const int* in_sizes, int n_in,
                              void* d_out, int out_size, void* d_ws, size_t ws_size,
                              hipStream_t stream) {
    const float* x      = (const float*)d_in[0];
    const float* q_w    = (const float*)d_in[1];
    const float* k_w    = (const float*)d_in[2];
    const float* v_w    = (const float*)d_in[3];
    const float* o_w    = (const float*)d_in[4];
    const float* temp   = (const float*)d_in[5];
    const float* ln1_w  = (const float*)d_in[6];
    const float* ln2_w  = (const float*)d_in[7];
    const float* gate_w = (const float*)d_in[8];
    const float* up_w   = (const float*)d_in[9];
    const float* gate2_w= (const float*)d_in[10];
    const float* down_w = (const float*)d_in[11];
    const float* ag_w   = (const float*)d_in[12];
    const float* ag_b   = (const float*)d_in[13];
    const float* fg_w   = (const float*)d_in[14];
    const float* fg_b   = (const float*)d_in[15];

    // ---- workspace regions (peak 251,658,240 B; lifetimes disjoint) ----
    char* ws = (char*)d_ws;
    u16*  Wbuf = (u16*)(ws);                      // 33,554,432 B  weight scratch (serial reuse)
    u16*  hbuf = (u16*)(ws + 33554432);           // 16,777,216 B  rmsnorm output
    float* x1  = (float*)(ws + 50331648);         // 33,554,432 B  post-attn residual (f32)
    u16*  combo= (u16*)(ws + 83886080);           // 67,108,864 B  [4096,8192] bf16
    char* E    = ws + 150994944;                  // 50,331,648 B  qkvact -> aof/aob -> ffn3q
    char* F    = ws + 201326592;                  // 33,554,432 B  attnb -> fff
    u16*  ffb  = (u16*)(ws + 234881024);          // 16,777,216 B

    u16*   qkvact = (u16*)E;                      // [4096,6144] bf16
    float* aof    = (float*)E;                    // [4096,2048] f32
    u16*   aob    = (u16*)(E + 33554432);         // [4096,2048] bf16
    u16*   ffn3q  = (u16*)E;                      // [4096,6144] bf16 (per quarter)
    u16*   attnb  = (u16*)F;                      // [4096,2048] bf16
    float* fff    = (float*)F;                    // [4096,2048] f32

    float* outp = (float*)d_out;
    const size_t DD = 2048ull * 2048ull;
    const int cg_d = (int)(DD / 4) / 256;         // 4096 blocks for a DxD weight

    // 1) h = rmsnorm(x, ln1)
    hipLaunchKernelGGL(rmsnorm_k, dim3(4096), dim3(256), 0, stream, x, ln1_w, hbuf);

    // 2) qkv = h @ [Wq;Wk;Wv]^T  (one GEMM, N=6144)
    hipLaunchKernelGGL(conv_bf16, dim3(cg_d), dim3(256), 0, stream, q_w, Wbuf,          (int)(DD / 4));
    hipLaunchKernelGGL(conv_bf16, dim3(cg_d), dim3(256), 0, stream, k_w, Wbuf + DD,     (int)(DD / 4));
    hipLaunchKernelGGL(conv_bf16, dim3(cg_d), dim3(256), 0, stream, v_w, Wbuf + 2 * DD, (int)(DD / 4));
    hipLaunchKernelGGL((gemm_bt<0>), dim3(32, 48), dim3(256), 0, stream,
                       hbuf, Wbuf, (float*)nullptr, qkvact,
                       (const float*)nullptr, (const float*)nullptr, (const float*)nullptr,
                       (float*)nullptr, 4096, 6144, 2048, 6144);

    // 3) l2-normalize q,k in place (q also scaled by temp[h])
    hipLaunchKernelGGL(qk_l2norm, dim3(32768), dim3(256), 0, stream, qkvact, temp);

    // 4) attention -> attnb
    hipLaunchKernelGGL(flash_attn, dim3(512), dim3(256), 0, stream, qkvact, attnb);

    // 5) attn_out = attn @ Wo^T
    hipLaunchKernelGGL(conv_bf16, dim3(cg_d), dim3(256), 0, stream, o_w, Wbuf, (int)(DD / 4));
    hipLaunchKernelGGL((gemm_bt<1>), dim3(32, 16), dim3(256), 0, stream,
                       attnb, Wbuf, aof, aob,
                       (const float*)nullptr, (const float*)nullptr, (const float*)nullptr,
                       (float*)nullptr, 4096, 2048, 2048, 2048);

    // 6) x1 = sigmoid(attn_out@Wag^T + b)*attn_out + (1-g)*x
    hipLaunchKernelGGL(conv_bf16, dim3(cg_d), dim3(256), 0, stream, ag_w, Wbuf, (int)(DD / 4));
    hipLaunchKernelGGL((gemm_bt<2>), dim3(32, 16), dim3(256), 0, stream,
                       aob, Wbuf, (float*)nullptr, (u16*)nullptr,
                       ag_b, aof, x, x1, 4096, 2048, 2048, 2048);

    // 7) h2 = rmsnorm(x1, ln2)
    hipLaunchKernelGGL(rmsnorm_k, dim3(4096), dim3(256), 0, stream, x1, ln2_w, hbuf);

    // 8) FFN in 4 HFF quarters
    for (int qd = 0; qd < 4; qd++) {
        const size_t wofs = (size_t)qd * 2048 * 2048;
        hipLaunchKernelGGL(conv_bf16, dim3(cg_d), dim3(256), 0, stream, gate_w + wofs,  Wbuf,                 (int)(DD / 4));
        hipLaunchKernelGGL(conv_bf16, dim3(cg_d), dim3(256), 0, stream, up_w + wofs,    Wbuf + 2048 * 2048,   (int)(DD / 4));
        hipLaunchKernelGGL(conv_bf16, dim3(cg_d), dim3(256), 0, stream, gate2_w + wofs, Wbuf + 2 * 2048 * 2048, (int)(DD / 4));
        hipLaunchKernelGGL((gemm_bt<0>), dim3(32, 48), dim3(256), 0, stream,
                           hbuf, Wbuf, (float*)nullptr, ffn3q,
                           (const float*)nullptr, (const float*)nullptr, (const float*)nullptr,
                           (float*)nullptr, 4096, 6144, 2048, 6144);
        hipLaunchKernelGGL(swiglu_comb, dim3(4096), dim3(256), 0, stream, ffn3q, combo + qd * 2048);
    }

    // 9) ffn_out = combo @ Wdn^T
    hipLaunchKernelGGL(conv_bf16, dim3(16384), dim3(256), 0, stream, down_w, Wbuf, (int)(2048ull * 8192 / 4));
    hipLaunchKernelGGL((gemm_bt<1>), dim3(32, 16), dim3(256), 0, stream,
                       combo, Wbuf, fff, ffb,
                       (const float*)nullptr, (const float*)nullptr, (const float*)nullptr,
                       (float*)nullptr, 4096, 2048, 8192, 2048);

    // 10) out = sigmoid(ffn_out@Wfg^T + b)*ffn_out + (1-g)*x1
    hipLaunchKernelGGL(conv_bf16, dim3(cg_d), dim3(256), 0, stream, fg_w, Wbuf, (int)(DD / 4));
    hipLaunchKernelGGL((gemm_bt<2>), dim3(32, 16), dim3(256), 0, stream,
                       ffb, Wbuf, (float*)nullptr, (u16*)nullptr,
                       fg_b, fff, x1, outp, 4096, 2048, 2048, 2048);
}

// Round 4
// 1261.355 us; speedup vs baseline: 1.3629x; 1.3104x over previous
//
#include <hip/hip_runtime.h>

typedef unsigned short u16;
typedef unsigned int u32;
using bf16x8 = __attribute__((ext_vector_type(8))) short;
using f32x4  = __attribute__((ext_vector_type(4))) float;

#define EPS 1e-5f

__device__ __forceinline__ u16 f2bf(float f) {
    union { float f; u32 u; } v; v.f = f;
    u32 r = v.u + 0x7FFFu + ((v.u >> 16) & 1u);   // RNE
    return (u16)(r >> 16);
}
__device__ __forceinline__ float bf2f(u16 u) {
    union { u32 u; float f; } v; v.u = ((u32)u) << 16;
    return v.f;
}
__device__ __forceinline__ void gl16(const void* g, void* s) {
    __builtin_amdgcn_global_load_lds(
        (const __attribute__((address_space(1))) u32*)g,
        (__attribute__((address_space(3))) u32*)s, 16, 0, 0);
}
__device__ __forceinline__ float sigm(float x) { return 1.f / (1.f + __expf(-x)); }

// ---------------- fp32 -> bf16 convert (grid = n/4 units) ----------------
__global__ void conv_bf16(const float* __restrict__ src, u16* __restrict__ dst, int n4) {
    int i = blockIdx.x * 256 + threadIdx.x;
    if (i >= n4) return;
    float4 v = reinterpret_cast<const float4*>(src)[i];
    u32 lo = (u32)f2bf(v.x) | ((u32)f2bf(v.y) << 16);
    u32 hi = (u32)f2bf(v.z) | ((u32)f2bf(v.w) << 16);
    reinterpret_cast<uint2*>(dst)[i] = make_uint2(lo, hi);
}

// ---------------- RMSNorm: fp32 [4096,2048] -> bf16, grid = 4096 rows ----------------
__global__ void rmsnorm_k(const float* __restrict__ x, const float* __restrict__ wt,
                          u16* __restrict__ out) {
    __shared__ float red[4];
    const int row = blockIdx.x, t = threadIdx.x;
    const float* xr = x + (size_t)row * 2048;
    float4 v0 = *reinterpret_cast<const float4*>(&xr[t * 8]);
    float4 v1 = *reinterpret_cast<const float4*>(&xr[t * 8 + 4]);
    float ss = v0.x*v0.x + v0.y*v0.y + v0.z*v0.z + v0.w*v0.w
             + v1.x*v1.x + v1.y*v1.y + v1.z*v1.z + v1.w*v1.w;
#pragma unroll
    for (int d = 1; d < 64; d <<= 1) ss += __shfl_xor(ss, d);
    if ((t & 63) == 0) red[t >> 6] = ss;
    __syncthreads();
    const float tot = red[0] + red[1] + red[2] + red[3];
    const float s = 1.f / sqrtf(tot * (1.f / 2048.f) + EPS);
    float4 w0 = *reinterpret_cast<const float4*>(&wt[t * 8]);
    float4 w1 = *reinterpret_cast<const float4*>(&wt[t * 8 + 4]);
    u32 o[4];
    o[0] = (u32)f2bf(v0.x * s * w0.x) | ((u32)f2bf(v0.y * s * w0.y) << 16);
    o[1] = (u32)f2bf(v0.z * s * w0.z) | ((u32)f2bf(v0.w * s * w0.w) << 16);
    o[2] = (u32)f2bf(v1.x * s * w1.x) | ((u32)f2bf(v1.y * s * w1.y) << 16);
    o[3] = (u32)f2bf(v1.z * s * w1.z) | ((u32)f2bf(v1.w * s * w1.w) << 16);
    *reinterpret_cast<uint4*>(&out[(size_t)row * 2048 + t * 8]) =
        make_uint4(o[0], o[1], o[2], o[3]);
}

// ---------------- L2 norm of q/k rows (in place); q additionally scaled by temp[h] ----------------
__global__ void qk_l2norm(u16* __restrict__ qkv, const float* __restrict__ temp) {
    const int wid = blockIdx.x * 4 + (threadIdx.x >> 6);
    const int l = threadIdx.x & 63;
    const int n = wid >> 5;
    const int rem = wid & 31;
    const int which = rem >> 4;   // 0=q, 1=k
    const int h = rem & 15;
    u16* p = qkv + (size_t)n * 6144 + which * 2048 + h * 128 + l * 2;
    u32 v = *reinterpret_cast<const u32*>(p);
    float f0 = bf2f((u16)(v & 0xffff)), f1 = bf2f((u16)(v >> 16));
    float ss = f0 * f0 + f1 * f1;
#pragma unroll
    for (int d = 1; d < 64; d <<= 1) ss += __shfl_xor(ss, d);
    float sc = 1.f / fmaxf(sqrtf(ss), 1e-12f);
    if (which == 0) sc *= temp[h];          // fold per-head temperature into q
    *reinterpret_cast<u32*>(p) = (u32)f2bf(f0 * sc) | ((u32)f2bf(f1 * sc) << 16);
}

// ---------------- generic NT GEMM: C[M,N] = A[M,K](bf16) x B[N,K](bf16)^T ----------------
template <int EPI>
__global__ void gemm_bt(const u16* __restrict__ A, const u16* __restrict__ B,
                        float* __restrict__ outF, u16* __restrict__ outB,
                        const float* __restrict__ bias, const float* __restrict__ addend,
                        const float* __restrict__ resid, float* __restrict__ outG,
                        int M, int N, int K, int ldc) {
    __shared__ u16 as_[128 * 32];
    __shared__ u16 bs_[128 * 32];
    const int t = threadIdx.x;
    const int bm = blockIdx.x, bn = blockIdx.y;
    const int w = t >> 6, l = t & 63;
    const int wr = w >> 1, wc = w & 1;
    const int lr = l & 15, lg = l >> 4;
    f32x4 acc[4][4];
#pragma unroll
    for (int i = 0; i < 4; i++)
#pragma unroll
        for (int j = 0; j < 4; j++) acc[i][j] = (f32x4){0.f, 0.f, 0.f, 0.f};

    const int r0 = t >> 2;
    const int c0 = (t & 3) << 3;
    const u16* aG = A + (size_t)(bm * 128 + r0) * K + c0;
    const u16* bG = B + (size_t)(bn * 128 + r0) * K + c0;
    const size_t step64 = (size_t)64 * K;
    u16* as0 = &as_[t * 8]; u16* as1 = &as_[2048 + t * 8];
    u16* bs0 = &bs_[t * 8]; u16* bs1 = &bs_[2048 + t * 8];

    for (int kt = 0; kt < K; kt += 32) {
        __syncthreads();
        gl16(aG + kt, as0);
        gl16(aG + step64 + kt, as1);
        gl16(bG + kt, bs0);
        gl16(bG + step64 + kt, bs1);
        __syncthreads();
        bf16x8 af[4], bf[4];
#pragma unroll
        for (int i = 0; i < 4; i++)
            af[i] = *reinterpret_cast<const bf16x8*>(&as_[(wr * 64 + i * 16 + lr) * 32 + lg * 8]);
#pragma unroll
        for (int j = 0; j < 4; j++)
            bf[j] = *reinterpret_cast<const bf16x8*>(&bs_[(wc * 64 + j * 16 + lr) * 32 + lg * 8]);
#pragma unroll
        for (int i = 0; i < 4; i++)
#pragma unroll
            for (int j = 0; j < 4; j++)
                acc[i][j] = __builtin_amdgcn_mfma_f32_16x16x32_bf16(af[i], bf[j], acc[i][j], 0, 0, 0);
    }
#pragma unroll
    for (int i = 0; i < 4; i++) {
        const int row = bm * 128 + wr * 64 + i * 16 + lg * 4;
#pragma unroll
        for (int j = 0; j < 4; j++) {
            const int col = bn * 128 + wc * 64 + j * 16 + lr;
#pragma unroll
            for (int q = 0; q < 4; q++) {
                const size_t idx = (size_t)(row + q) * ldc + col;
                const float v = acc[i][j][q];
                if (EPI == 0) {
                    outB[idx] = f2bf(v);
                } else if (EPI == 1) {
                    outF[idx] = v;
                    outB[idx] = f2bf(v);
                } else {
                    const float g = sigm(v + bias[col]);
                    outG[idx] = g * addend[idx] + (1.f - g) * resid[idx];
                }
            }
        }
    }
}

// ---------------- causal flash attention (QBLK=128, 8 waves, reg-staged dbuf pipeline) ----------------
// qkv: [4096, 6144] bf16 (q pre-scaled by temp & l2-normed, k l2-normed, v raw)
// grid: 256 blocks x 512 thr. Block p handles q-tiles p and 15-p of one (b,h);
// all 8 blocks of a head map to one XCD (dispatch-order heuristic).
#define VSWZ(dh) (((((dh) >> 3) ^ (dh)) & 7) << 4)
__global__ __launch_bounds__(512) void flash_attn(const u16* __restrict__ qkv,
                                                  u16* __restrict__ out) {
    __shared__ u16 klds[2][64 * 128];
    __shared__ u16 vlds[2][128 * 64];   // V^T, swizzled
    __shared__ u16 plds[8][16 * 64];
    const int t = threadIdx.x, w = t >> 6, l = t & 63;
    const int lr = l & 15, lg = l >> 4;
    const int b0 = blockIdx.x;
    const int xcd = b0 & 7, i0 = b0 >> 3;       // i0: 0..31
    const int bh = ((i0 & 3) << 3) | xcd;       // 8 blocks of a head share b0&7
    const int p = i0 >> 2;                      // 0..7
    const int b = bh >> 4, h = bh & 15;
    const size_t base = (size_t)b * 2048;
    // staging geometry: 64x128 tile = 1024 16B-chunks; thread t does rows sr0, sr0+32
    const int sr0 = t >> 4;                     // 0..31
    const int sc0 = (t & 15) << 3;              // dh 0..120

    uint4 kreg0, kreg1, vreg0, vreg1;

#define STAGE_LOAD(KT) do {                                                          \
        const size_t gg = (base + (size_t)(KT) * 64 + sr0) * 6144 + h * 128 + sc0;   \
        kreg0 = *reinterpret_cast<const uint4*>(&qkv[gg + 2048]);                    \
        vreg0 = *reinterpret_cast<const uint4*>(&qkv[gg + 4096]);                    \
        kreg1 = *reinterpret_cast<const uint4*>(&qkv[gg + 32 * 6144 + 2048]);        \
        vreg1 = *reinterpret_cast<const uint4*>(&qkv[gg + 32 * 6144 + 4096]);        \
    } while (0)

#define STAGE_WRITE(BUF) do {                                                                     \
        char* kb = (char*)&klds[BUF][0];                                                          \
        char* vb = (char*)&vlds[BUF][0];                                                          \
        *reinterpret_cast<uint4*>(kb + ((sr0 * 256 + sc0 * 2) ^ ((sr0 & 7) << 4))) = kreg0;       \
        *reinterpret_cast<uint4*>(kb + (((sr0 + 32) * 256 + sc0 * 2) ^ ((sr0 & 7) << 4))) = kreg1;\
        union { uint4 u; u16 s[8]; } vv;                                                          \
        vv.u = vreg0;                                                                             \
        _Pragma("unroll")                                                                         \
        for (int jj = 0; jj < 8; jj++) {                                                          \
            const int dh = sc0 + jj;                                                              \
            *reinterpret_cast<u16*>(vb + ((dh * 128 + sr0 * 2) ^ VSWZ(dh))) = vv.s[jj];           \
        }                                                                                         \
        vv.u = vreg1;                                                                             \
        _Pragma("unroll")                                                                         \
        for (int jj = 0; jj < 8; jj++) {                                                          \
            const int dh = sc0 + jj;                                                              \
            *reinterpret_cast<u16*>(vb + ((dh * 128 + (sr0 + 32) * 2) ^ VSWZ(dh))) = vv.s[jj];    \
        }                                                                                         \
    } while (0)

    for (int phase = 0; phase < 2; ++phase) {
        const int qt = phase ? (15 - p) : p;
        const int last = 2 * qt + 1;
        const int qrow = qt * 128 + w * 16 + lr;     // A-frag rows (within batch)
        const int qr0 = qt * 128 + w * 16 + lg * 4;  // C rows base
        bf16x8 qf[4];
#pragma unroll
        for (int kk = 0; kk < 4; kk++)
            qf[kk] = *reinterpret_cast<const bf16x8*>(
                &qkv[(base + qrow) * 6144 + h * 128 + kk * 32 + lg * 8]);
        f32x4 o[8];
#pragma unroll
        for (int i = 0; i < 8; i++) o[i] = (f32x4){0.f, 0.f, 0.f, 0.f};
        float m[4] = {-1e30f, -1e30f, -1e30f, -1e30f};
        float ls[4] = {0.f, 0.f, 0.f, 0.f};

        // prologue: stage tile 0
        STAGE_LOAD(0);
        int cur = 0;
        STAGE_WRITE(0);
        __syncthreads();

        for (int kt = 0; kt <= last; ++kt) {
            if (kt < last) STAGE_LOAD(kt + 1);     // issue next-tile loads early
            const char* kb = (const char*)&klds[cur][0];
            const char* vb = (const char*)&vlds[cur][0];
            // S = Q K^T  (16 x 64 per wave)
            f32x4 s[4];
#pragma unroll
            for (int nf = 0; nf < 4; nf++) {
                f32x4 a = (f32x4){0.f, 0.f, 0.f, 0.f};
                const int kv = nf * 16 + lr;
#pragma unroll
                for (int kk = 0; kk < 4; kk++) {
                    bf16x8 kf = *reinterpret_cast<const bf16x8*>(
                        kb + ((kv * 256 + kk * 64 + lg * 16) ^ ((kv & 7) << 4)));
                    a = __builtin_amdgcn_mfma_f32_16x16x32_bf16(qf[kk], kf, a, 0, 0, 0);
                }
                s[nf] = a;
            }
            // causal mask (only diagonal-range tiles)
            if (kt >= 2 * qt) {
#pragma unroll
                for (int nf = 0; nf < 4; nf++) {
                    const int kvi = kt * 64 + nf * 16 + lr;
#pragma unroll
                    for (int q = 0; q < 4; q++)
                        if (kvi > qr0 + q) s[nf][q] = -1e30f;
                }
            }
            // online softmax
            float mx[4] = {-1e30f, -1e30f, -1e30f, -1e30f};
#pragma unroll
            for (int nf = 0; nf < 4; nf++)
#pragma unroll
                for (int q = 0; q < 4; q++) mx[q] = fmaxf(mx[q], s[nf][q]);
#pragma unroll
            for (int q = 0; q < 4; q++) {
#pragma unroll
                for (int d = 1; d < 16; d <<= 1) mx[q] = fmaxf(mx[q], __shfl_xor(mx[q], d));
            }
            float fac[4], rs[4];
#pragma unroll
            for (int q = 0; q < 4; q++) {
                const float mn = fmaxf(m[q], mx[q]);
                fac[q] = __expf(m[q] - mn);
                m[q] = mn;
                rs[q] = 0.f;
            }
#pragma unroll
            for (int nf = 0; nf < 4; nf++) {
#pragma unroll
                for (int q = 0; q < 4; q++) {
                    const float pv = __expf(s[nf][q] - m[q]);
                    s[nf][q] = pv;
                    rs[q] += pv;
                }
            }
            // P -> LDS (per-wave, swizzled)
#pragma unroll
            for (int nf = 0; nf < 4; nf++) {
                const int col = nf * 16 + lr;
#pragma unroll
                for (int q = 0; q < 4; q++) {
                    const int row = lg * 4 + q;
                    *reinterpret_cast<u16*>((char*)&plds[w][0] +
                        ((row * 128 + col * 2) ^ ((row & 7) << 4))) = f2bf(s[nf][q]);
                }
            }
#pragma unroll
            for (int q = 0; q < 4; q++) {
#pragma unroll
                for (int d = 1; d < 16; d <<= 1) rs[q] += __shfl_xor(rs[q], d);
                ls[q] = ls[q] * fac[q] + rs[q];
            }
#pragma unroll
            for (int nf2 = 0; nf2 < 8; nf2++)
#pragma unroll
                for (int q = 0; q < 4; q++) o[nf2][q] *= fac[q];
            // O += P V
#pragma unroll
            for (int ks = 0; ks < 2; ks++) {
                bf16x8 pf = *reinterpret_cast<const bf16x8*>((char*)&plds[w][0] +
                    ((lr * 128 + ks * 64 + lg * 16) ^ ((lr & 7) << 4)));
#pragma unroll
                for (int nf2 = 0; nf2 < 8; nf2++) {
                    const int dh = nf2 * 16 + lr;
                    bf16x8 vf = *reinterpret_cast<const bf16x8*>(
                        vb + ((dh * 128 + ks * 64 + lg * 16) ^ VSWZ(dh)));
                    o[nf2] = __builtin_amdgcn_mfma_f32_16x16x32_bf16(pf, vf, o[nf2], 0, 0, 0);
                }
            }
            // write next tile into the other buffer; one barrier per step
            if (kt < last) STAGE_WRITE(cur ^ 1);
            __syncthreads();
            cur ^= 1;
        }
#pragma unroll
        for (int nf2 = 0; nf2 < 8; nf2++) {
            const int col = h * 128 + nf2 * 16 + lr;
#pragma unroll
            for (int q = 0; q < 4; q++) {
                const float v = o[nf2][q] / ls[q];
                out[(base + qr0 + q) * 2048 + col] = f2bf(v);
            }
        }
        __syncthreads();
    }
#undef STAGE_LOAD
#undef STAGE_WRITE
}

// ---------------- SwiGLU combine (one HFF quarter) ----------------
__global__ void swiglu_comb(const u16* __restrict__ f3, u16* __restrict__ comb) {
    const size_t u = (size_t)blockIdx.x * 256 + threadIdx.x;  // 8-elem units of [4096,2048]
    const size_t n = u >> 8;
    const int f = (int)(u & 255) << 3;
    const u16* gp = f3 + n * 6144 + f;
    union { uint4 q; u16 s[8]; } g, up, g2;
    g.q  = *reinterpret_cast<const uint4*>(gp);
    up.q = *reinterpret_cast<const uint4*>(gp + 2048);
    g2.q = *reinterpret_cast<const uint4*>(gp + 4096);
    u32 r[4];
#pragma unroll
    for (int i = 0; i < 4; i++) {
        float a0 = bf2f(g.s[2 * i]),     a1 = bf2f(g.s[2 * i + 1]);
        float b0 = bf2f(up.s[2 * i]),    b1 = bf2f(up.s[2 * i + 1]);
        float c0 = bf2f(g2.s[2 * i]),    c1 = bf2f(g2.s[2 * i + 1]);
        float r0 = a0 * sigm(a0) * b0 * sigm(c0);
        float r1 = a1 * sigm(a1) * b1 * sigm(c1);
        r[i] = (u32)f2bf(r0) | ((u32)f2bf(r1) << 16);
    }
    *reinterpret_cast<uint4*>(comb + n * 8192 + f) = make_uint4(r[0], r[1], r[2], r[3]);
}

// ---------------- launch ----------------
extern "C" void kernel_launch(void* const* d_in, const int* in_sizes, int n_in,
                              void* d_out, int out_size, void* d_ws, size_t ws_size,
                              hipStream_t stream) {
    const float* x      = (const float*)d_in[0];
    const float* q_w    = (const float*)d_in[1];
    const float* k_w    = (const float*)d_in[2];
    const float* v_w    = (const float*)d_in[3];
    const float* o_w    = (const float*)d_in[4];
    const float* temp   = (const float*)d_in[5];
    const float* ln1_w  = (const float*)d_in[6];
    const float* ln2_w  = (const float*)d_in[7];
    const float* gate_w = (const float*)d_in[8];
    const float* up_w   = (const float*)d_in[9];
    const float* gate2_w= (const float*)d_in[10];
    const float* down_w = (const float*)d_in[11];
    const float* ag_w   = (const float*)d_in[12];
    const float* ag_b   = (const float*)d_in[13];
    const float* fg_w   = (const float*)d_in[14];
    const float* fg_b   = (const float*)d_in[15];

    // ---- workspace regions (peak 251,658,240 B; lifetimes disjoint) ----
    char* ws = (char*)d_ws;
    u16*  Wbuf = (u16*)(ws);                      // 33,554,432 B  weight scratch (serial reuse)
    u16*  hbuf = (u16*)(ws + 33554432);           // 16,777,216 B  rmsnorm output
    float* x1  = (float*)(ws + 50331648);         // 33,554,432 B  post-attn residual (f32)
    u16*  combo= (u16*)(ws + 83886080);           // 67,108,864 B  [4096,8192] bf16
    char* E    = ws + 150994944;                  // 50,331,648 B  qkvact -> aof/aob -> ffn3q
    char* F    = ws + 201326592;                  // 33,554,432 B  attnb -> fff
    u16*  ffb  = (u16*)(ws + 234881024);          // 16,777,216 B

    u16*   qkvact = (u16*)E;                      // [4096,6144] bf16
    float* aof    = (float*)E;                    // [4096,2048] f32
    u16*   aob    = (u16*)(E + 33554432);         // [4096,2048] bf16
    u16*   ffn3q  = (u16*)E;                      // [4096,6144] bf16 (per quarter)
    u16*   attnb  = (u16*)F;                      // [4096,2048] bf16
    float* fff    = (float*)F;                    // [4096,2048] f32

    float* outp = (float*)d_out;
    const size_t DD = 2048ull * 2048ull;
    const int cg_d = (int)(DD / 4) / 256;         // 4096 blocks for a DxD weight

    // 1) h = rmsnorm(x, ln1)
    hipLaunchKernelGGL(rmsnorm_k, dim3(4096), dim3(256), 0, stream, x, ln1_w, hbuf);

    // 2) qkv = h @ [Wq;Wk;Wv]^T  (one GEMM, N=6144)
    hipLaunchKernelGGL(conv_bf16, dim3(cg_d), dim3(256), 0, stream, q_w, Wbuf,          (int)(DD / 4));
    hipLaunchKernelGGL(conv_bf16, dim3(cg_d), dim3(256), 0, stream, k_w, Wbuf + DD,     (int)(DD / 4));
    hipLaunchKernelGGL(conv_bf16, dim3(cg_d), dim3(256), 0, stream, v_w, Wbuf + 2 * DD, (int)(DD / 4));
    hipLaunchKernelGGL((gemm_bt<0>), dim3(32, 48), dim3(256), 0, stream,
                       hbuf, Wbuf, (float*)nullptr, qkvact,
                       (const float*)nullptr, (const float*)nullptr, (const float*)nullptr,
                       (float*)nullptr, 4096, 6144, 2048, 6144);

    // 3) l2-normalize q,k in place (q also scaled by temp[h])
    hipLaunchKernelGGL(qk_l2norm, dim3(32768), dim3(256), 0, stream, qkvact, temp);

    // 4) attention -> attnb
    hipLaunchKernelGGL(flash_attn, dim3(256), dim3(512), 0, stream, qkvact, attnb);

    // 5) attn_out = attn @ Wo^T
    hipLaunchKernelGGL(conv_bf16, dim3(cg_d), dim3(256), 0, stream, o_w, Wbuf, (int)(DD / 4));
    hipLaunchKernelGGL((gemm_bt<1>), dim3(32, 16), dim3(256), 0, stream,
                       attnb, Wbuf, aof, aob,
                       (const float*)nullptr, (const float*)nullptr, (const float*)nullptr,
                       (float*)nullptr, 4096, 2048, 2048, 2048);

    // 6) x1 = sigmoid(attn_out@Wag^T + b)*attn_out + (1-g)*x
    hipLaunchKernelGGL(conv_bf16, dim3(cg_d), dim3(256), 0, stream, ag_w, Wbuf, (int)(DD / 4));
    hipLaunchKernelGGL((gemm_bt<2>), dim3(32, 16), dim3(256), 0, stream,
                       aob, Wbuf, (float*)nullptr, (u16*)nullptr,
                       ag_b, aof, x, x1, 4096, 2048, 2048, 2048);

    // 7) h2 = rmsnorm(x1, ln2)
    hipLaunchKernelGGL(rmsnorm_k, dim3(4096), dim3(256), 0, stream, x1, ln2_w, hbuf);

    // 8) FFN in 4 HFF quarters
    for (int qd = 0; qd < 4; qd++) {
        const size_t wofs = (size_t)qd * 2048 * 2048;
        hipLaunchKernelGGL(conv_bf16, dim3(cg_d), dim3(256), 0, stream, gate_w + wofs,  Wbuf,                 (int)(DD / 4));
        hipLaunchKernelGGL(conv_bf16, dim3(cg_d), dim3(256), 0, stream, up_w + wofs,    Wbuf + 2048 * 2048,   (int)(DD / 4));
        hipLaunchKernelGGL(conv_bf16, dim3(cg_d), dim3(256), 0, stream, gate2_w + wofs, Wbuf + 2 * 2048 * 2048, (int)(DD / 4));
        hipLaunchKernelGGL((gemm_bt<0>), dim3(32, 48), dim3(256), 0, stream,
                           hbuf, Wbuf, (float*)nullptr, ffn3q,
                           (const float*)nullptr, (const float*)nullptr, (const float*)nullptr,
                           (float*)nullptr, 4096, 6144, 2048, 6144);
        hipLaunchKernelGGL(swiglu_comb, dim3(4096), dim3(256), 0, stream, ffn3q, combo + qd * 2048);
    }

    // 9) ffn_out = combo @ Wdn^T
    hipLaunchKernelGGL(conv_bf16, dim3(16384), dim3(256), 0, stream, down_w, Wbuf, (int)(2048ull * 8192 / 4));
    hipLaunchKernelGGL((gemm_bt<1>), dim3(32, 16), dim3(256), 0, stream,
                       combo, Wbuf, fff, ffb,
                       (const float*)nullptr, (const float*)nullptr, (const float*)nullptr,
                       (float*)nullptr, 4096, 2048, 8192, 2048);

    // 10) out = sigmoid(ffn_out@Wfg^T + b)*ffn_out + (1-g)*x1
    hipLaunchKernelGGL(conv_bf16, dim3(cg_d), dim3(256), 0, stream, fg_w, Wbuf, (int)(DD / 4));
    hipLaunchKernelGGL((gemm_bt<2>), dim3(32, 16), dim3(256), 0, stream,
                       ffb, Wbuf, (float*)nullptr, (u16*)nullptr,
                       fg_b, fff, x1, outp, 4096, 2048, 2048, 2048);
}

// Round 5
// 1248.478 us; speedup vs baseline: 1.3770x; 1.0103x over previous
//
#include <hip/hip_runtime.h>

typedef unsigned short u16;
typedef unsigned int u32;
using bf16x8 = __attribute__((ext_vector_type(8))) short;
using f32x4  = __attribute__((ext_vector_type(4))) float;

#define EPS 1e-5f

__device__ __forceinline__ u16 f2bf(float f) {
    union { float f; u32 u; } v; v.f = f;
    u32 r = v.u + 0x7FFFu + ((v.u >> 16) & 1u);   // RNE
    return (u16)(r >> 16);
}
__device__ __forceinline__ float bf2f(u16 u) {
    union { u32 u; float f; } v; v.u = ((u32)u) << 16;
    return v.f;
}
__device__ __forceinline__ void gl16(const void* g, void* s) {
    __builtin_amdgcn_global_load_lds(
        (const __attribute__((address_space(1))) u32*)g,
        (__attribute__((address_space(3))) u32*)s, 16, 0, 0);
}
__device__ __forceinline__ float sigm(float x) { return 1.f / (1.f + __expf(-x)); }

// ---------------- fp32 -> bf16 convert (grid = n/4 units) ----------------
__global__ void conv_bf16(const float* __restrict__ src, u16* __restrict__ dst, int n4) {
    int i = blockIdx.x * 256 + threadIdx.x;
    if (i >= n4) return;
    float4 v = reinterpret_cast<const float4*>(src)[i];
    u32 lo = (u32)f2bf(v.x) | ((u32)f2bf(v.y) << 16);
    u32 hi = (u32)f2bf(v.z) | ((u32)f2bf(v.w) << 16);
    reinterpret_cast<uint2*>(dst)[i] = make_uint2(lo, hi);
}

// triple variant: blockIdx.y selects (src,dst) pair; all same length n4
__global__ void conv3_bf16(const float* __restrict__ s0, const float* __restrict__ s1,
                           const float* __restrict__ s2, u16* __restrict__ d0,
                           u16* __restrict__ d1, u16* __restrict__ d2, int n4) {
    int i = blockIdx.x * 256 + threadIdx.x;
    if (i >= n4) return;
    const float* src = (blockIdx.y == 0) ? s0 : (blockIdx.y == 1) ? s1 : s2;
    u16* dst = (blockIdx.y == 0) ? d0 : (blockIdx.y == 1) ? d1 : d2;
    float4 v = reinterpret_cast<const float4*>(src)[i];
    u32 lo = (u32)f2bf(v.x) | ((u32)f2bf(v.y) << 16);
    u32 hi = (u32)f2bf(v.z) | ((u32)f2bf(v.w) << 16);
    reinterpret_cast<uint2*>(dst)[i] = make_uint2(lo, hi);
}

// ---------------- RMSNorm: fp32 [4096,2048] -> bf16, grid = 4096 rows ----------------
__global__ void rmsnorm_k(const float* __restrict__ x, const float* __restrict__ wt,
                          u16* __restrict__ out) {
    __shared__ float red[4];
    const int row = blockIdx.x, t = threadIdx.x;
    const float* xr = x + (size_t)row * 2048;
    float4 v0 = *reinterpret_cast<const float4*>(&xr[t * 8]);
    float4 v1 = *reinterpret_cast<const float4*>(&xr[t * 8 + 4]);
    float ss = v0.x*v0.x + v0.y*v0.y + v0.z*v0.z + v0.w*v0.w
             + v1.x*v1.x + v1.y*v1.y + v1.z*v1.z + v1.w*v1.w;
#pragma unroll
    for (int d = 1; d < 64; d <<= 1) ss += __shfl_xor(ss, d);
    if ((t & 63) == 0) red[t >> 6] = ss;
    __syncthreads();
    const float tot = red[0] + red[1] + red[2] + red[3];
    const float s = 1.f / sqrtf(tot * (1.f / 2048.f) + EPS);
    float4 w0 = *reinterpret_cast<const float4*>(&wt[t * 8]);
    float4 w1 = *reinterpret_cast<const float4*>(&wt[t * 8 + 4]);
    u32 o[4];
    o[0] = (u32)f2bf(v0.x * s * w0.x) | ((u32)f2bf(v0.y * s * w0.y) << 16);
    o[1] = (u32)f2bf(v0.z * s * w0.z) | ((u32)f2bf(v0.w * s * w0.w) << 16);
    o[2] = (u32)f2bf(v1.x * s * w1.x) | ((u32)f2bf(v1.y * s * w1.y) << 16);
    o[3] = (u32)f2bf(v1.z * s * w1.z) | ((u32)f2bf(v1.w * s * w1.w) << 16);
    *reinterpret_cast<uint4*>(&out[(size_t)row * 2048 + t * 8]) =
        make_uint4(o[0], o[1], o[2], o[3]);
}

// ---------------- L2 norm of q/k rows (in place); q additionally scaled by temp[h] ----------------
__global__ void qk_l2norm(u16* __restrict__ qkv, const float* __restrict__ temp) {
    const int wid = blockIdx.x * 4 + (threadIdx.x >> 6);
    const int l = threadIdx.x & 63;
    const int n = wid >> 5;
    const int rem = wid & 31;
    const int which = rem >> 4;   // 0=q, 1=k
    const int h = rem & 15;
    u16* p = qkv + (size_t)n * 6144 + which * 2048 + h * 128 + l * 2;
    u32 v = *reinterpret_cast<const u32*>(p);
    float f0 = bf2f((u16)(v & 0xffff)), f1 = bf2f((u16)(v >> 16));
    float ss = f0 * f0 + f1 * f1;
#pragma unroll
    for (int d = 1; d < 64; d <<= 1) ss += __shfl_xor(ss, d);
    float sc = 1.f / fmaxf(sqrtf(ss), 1e-12f);
    if (which == 0) sc *= temp[h];          // fold per-head temperature into q
    *reinterpret_cast<u32*>(p) = (u32)f2bf(f0 * sc) | ((u32)f2bf(f1 * sc) << 16);
}

// ---------------- generic NT GEMM: C[M,N] = A[M,K](bf16) x B[N,K](bf16)^T ----------------
// 1D grid = (M/128)*(N/128). Bijective XCD chunking (m204) + 8-wide bm supertile
// rasterization: each XCD works on 8 A-panels (4MB, L2-resident) sweeping bn.
template <int EPI>
__global__ void gemm_bt(const u16* __restrict__ A, const u16* __restrict__ B,
                        float* __restrict__ outF, u16* __restrict__ outB,
                        const float* __restrict__ bias, const float* __restrict__ addend,
                        const float* __restrict__ resid, float* __restrict__ outG,
                        int M, int N, int K, int ldc) {
    __shared__ u16 as_[128 * 32];
    __shared__ u16 bs_[128 * 32];
    const int nbn = N >> 7;
    const int nwg = (M >> 7) * nbn;
    // XCD chunking: orig = lin*8 + xcd -> wgid contiguous per XCD
    {
    }
    const int orig = blockIdx.x;
    const int q8 = nwg >> 3, r8 = nwg & 7;
    const int xcd = orig & 7, lin = orig >> 3;
    const int wgid = (xcd < r8 ? xcd * (q8 + 1) : r8 * (q8 + 1) + (xcd - r8) * q8) + lin;
    // supertile raster: 8 bm-rows x full bn sweep
    const int g = wgid / (nbn << 3);
    const int rem = wgid - g * (nbn << 3);
    const int bn = rem >> 3;
    const int bm = (g << 3) + (rem & 7);

    const int t = threadIdx.x;
    const int w = t >> 6, l = t & 63;
    const int wr = w >> 1, wc = w & 1;
    const int lr = l & 15, lg = l >> 4;
    f32x4 acc[4][4];
#pragma unroll
    for (int i = 0; i < 4; i++)
#pragma unroll
        for (int j = 0; j < 4; j++) acc[i][j] = (f32x4){0.f, 0.f, 0.f, 0.f};

    const int r0 = t >> 2;
    const int c0 = (t & 3) << 3;
    const u16* aG = A + (size_t)(bm * 128 + r0) * K + c0;
    const u16* bG = B + (size_t)(bn * 128 + r0) * K + c0;
    const size_t step64 = (size_t)64 * K;
    u16* as0 = &as_[t * 8]; u16* as1 = &as_[2048 + t * 8];
    u16* bs0 = &bs_[t * 8]; u16* bs1 = &bs_[2048 + t * 8];

    for (int kt = 0; kt < K; kt += 32) {
        __syncthreads();
        gl16(aG + kt, as0);
        gl16(aG + step64 + kt, as1);
        gl16(bG + kt, bs0);
        gl16(bG + step64 + kt, bs1);
        __syncthreads();
        bf16x8 af[4], bf[4];
#pragma unroll
        for (int i = 0; i < 4; i++)
            af[i] = *reinterpret_cast<const bf16x8*>(&as_[(wr * 64 + i * 16 + lr) * 32 + lg * 8]);
#pragma unroll
        for (int j = 0; j < 4; j++)
            bf[j] = *reinterpret_cast<const bf16x8*>(&bs_[(wc * 64 + j * 16 + lr) * 32 + lg * 8]);
#pragma unroll
        for (int i = 0; i < 4; i++)
#pragma unroll
            for (int j = 0; j < 4; j++)
                acc[i][j] = __builtin_amdgcn_mfma_f32_16x16x32_bf16(af[i], bf[j], acc[i][j], 0, 0, 0);
    }
#pragma unroll
    for (int i = 0; i < 4; i++) {
        const int row = bm * 128 + wr * 64 + i * 16 + lg * 4;
#pragma unroll
        for (int j = 0; j < 4; j++) {
            const int col = bn * 128 + wc * 64 + j * 16 + lr;
#pragma unroll
            for (int q = 0; q < 4; q++) {
                const size_t idx = (size_t)(row + q) * ldc + col;
                const float v = acc[i][j][q];
                if (EPI == 0) {
                    outB[idx] = f2bf(v);
                } else if (EPI == 1) {
                    outF[idx] = v;
                    outB[idx] = f2bf(v);
                } else {
                    const float g2 = sigm(v + bias[col]);
                    outG[idx] = g2 * addend[idx] + (1.f - g2) * resid[idx];
                }
            }
        }
    }
}

// ---------------- causal flash attention (QBLK=128, 8 waves, reg-staged dbuf pipeline) ----------------
#define VSWZ(dh) (((((dh) >> 3) ^ (dh)) & 7) << 4)
__global__ __launch_bounds__(512) void flash_attn(const u16* __restrict__ qkv,
                                                  u16* __restrict__ out) {
    __shared__ u16 klds[2][64 * 128];
    __shared__ u16 vlds[2][128 * 64];   // V^T, swizzled
    __shared__ u16 plds[8][16 * 64];
    const int t = threadIdx.x, w = t >> 6, l = t & 63;
    const int lr = l & 15, lg = l >> 4;
    const int b0 = blockIdx.x;
    const int xcd = b0 & 7, i0 = b0 >> 3;       // i0: 0..31
    const int bh = ((i0 & 3) << 3) | xcd;       // 8 blocks of a head share b0&7
    const int p = i0 >> 2;                      // 0..7
    const int b = bh >> 4, h = bh & 15;
    const size_t base = (size_t)b * 2048;
    const int sr0 = t >> 4;                     // 0..31
    const int sc0 = (t & 15) << 3;              // dh 0..120

    uint4 kreg0, kreg1, vreg0, vreg1;

#define STAGE_LOAD(KT) do {                                                          \
        const size_t gg = (base + (size_t)(KT) * 64 + sr0) * 6144 + h * 128 + sc0;   \
        kreg0 = *reinterpret_cast<const uint4*>(&qkv[gg + 2048]);                    \
        vreg0 = *reinterpret_cast<const uint4*>(&qkv[gg + 4096]);                    \
        kreg1 = *reinterpret_cast<const uint4*>(&qkv[gg + 32 * 6144 + 2048]);        \
        vreg1 = *reinterpret_cast<const uint4*>(&qkv[gg + 32 * 6144 + 4096]);        \
    } while (0)

#define STAGE_WRITE(BUF) do {                                                                     \
        char* kb = (char*)&klds[BUF][0];                                                          \
        char* vb = (char*)&vlds[BUF][0];                                                          \
        *reinterpret_cast<uint4*>(kb + ((sr0 * 256 + sc0 * 2) ^ ((sr0 & 7) << 4))) = kreg0;       \
        *reinterpret_cast<uint4*>(kb + (((sr0 + 32) * 256 + sc0 * 2) ^ ((sr0 & 7) << 4))) = kreg1;\
        union { uint4 u; u16 s[8]; } vv;                                                          \
        vv.u = vreg0;                                                                             \
        _Pragma("unroll")                                                                         \
        for (int jj = 0; jj < 8; jj++) {                                                          \
            const int dh = sc0 + jj;                                                              \
            *reinterpret_cast<u16*>(vb + ((dh * 128 + sr0 * 2) ^ VSWZ(dh))) = vv.s[jj];           \
        }                                                                                         \
        vv.u = vreg1;                                                                             \
        _Pragma("unroll")                                                                         \
        for (int jj = 0; jj < 8; jj++) {                                                          \
            const int dh = sc0 + jj;                                                              \
            *reinterpret_cast<u16*>(vb + ((dh * 128 + (sr0 + 32) * 2) ^ VSWZ(dh))) = vv.s[jj];    \
        }                                                                                         \
    } while (0)

    for (int phase = 0; phase < 2; ++phase) {
        const int qt = phase ? (15 - p) : p;
        const int last = 2 * qt + 1;
        const int qrow = qt * 128 + w * 16 + lr;
        const int qr0 = qt * 128 + w * 16 + lg * 4;
        bf16x8 qf[4];
#pragma unroll
        for (int kk = 0; kk < 4; kk++)
            qf[kk] = *reinterpret_cast<const bf16x8*>(
                &qkv[(base + qrow) * 6144 + h * 128 + kk * 32 + lg * 8]);
        f32x4 o[8];
#pragma unroll
        for (int i = 0; i < 8; i++) o[i] = (f32x4){0.f, 0.f, 0.f, 0.f};
        float m[4] = {-1e30f, -1e30f, -1e30f, -1e30f};
        float ls[4] = {0.f, 0.f, 0.f, 0.f};

        STAGE_LOAD(0);
        int cur = 0;
        STAGE_WRITE(0);
        __syncthreads();

        for (int kt = 0; kt <= last; ++kt) {
            if (kt < last) STAGE_LOAD(kt + 1);
            const char* kb = (const char*)&klds[cur][0];
            const char* vb = (const char*)&vlds[cur][0];
            f32x4 s[4];
#pragma unroll
            for (int nf = 0; nf < 4; nf++) {
                f32x4 a = (f32x4){0.f, 0.f, 0.f, 0.f};
                const int kv = nf * 16 + lr;
#pragma unroll
                for (int kk = 0; kk < 4; kk++) {
                    bf16x8 kf = *reinterpret_cast<const bf16x8*>(
                        kb + ((kv * 256 + kk * 64 + lg * 16) ^ ((kv & 7) << 4)));
                    a = __builtin_amdgcn_mfma_f32_16x16x32_bf16(qf[kk], kf, a, 0, 0, 0);
                }
                s[nf] = a;
            }
            if (kt >= 2 * qt) {
#pragma unroll
                for (int nf = 0; nf < 4; nf++) {
                    const int kvi = kt * 64 + nf * 16 + lr;
#pragma unroll
                    for (int q = 0; q < 4; q++)
                        if (kvi > qr0 + q) s[nf][q] = -1e30f;
                }
            }
            float mx[4] = {-1e30f, -1e30f, -1e30f, -1e30f};
#pragma unroll
            for (int nf = 0; nf < 4; nf++)
#pragma unroll
                for (int q = 0; q < 4; q++) mx[q] = fmaxf(mx[q], s[nf][q]);
#pragma unroll
            for (int q = 0; q < 4; q++) {
#pragma unroll
                for (int d = 1; d < 16; d <<= 1) mx[q] = fmaxf(mx[q], __shfl_xor(mx[q], d));
            }
            float fac[4], rs[4];
#pragma unroll
            for (int q = 0; q < 4; q++) {
                const float mn = fmaxf(m[q], mx[q]);
                fac[q] = __expf(m[q] - mn);
                m[q] = mn;
                rs[q] = 0.f;
            }
#pragma unroll
            for (int nf = 0; nf < 4; nf++) {
#pragma unroll
                for (int q = 0; q < 4; q++) {
                    const float pv = __expf(s[nf][q] - m[q]);
                    s[nf][q] = pv;
                    rs[q] += pv;
                }
            }
#pragma unroll
            for (int nf = 0; nf < 4; nf++) {
                const int col = nf * 16 + lr;
#pragma unroll
                for (int q = 0; q < 4; q++) {
                    const int row = lg * 4 + q;
                    *reinterpret_cast<u16*>((char*)&plds[w][0] +
                        ((row * 128 + col * 2) ^ ((row & 7) << 4))) = f2bf(s[nf][q]);
                }
            }
#pragma unroll
            for (int q = 0; q < 4; q++) {
#pragma unroll
                for (int d = 1; d < 16; d <<= 1) rs[q] += __shfl_xor(rs[q], d);
                ls[q] = ls[q] * fac[q] + rs[q];
            }
#pragma unroll
            for (int nf2 = 0; nf2 < 8; nf2++)
#pragma unroll
                for (int q = 0; q < 4; q++) o[nf2][q] *= fac[q];
#pragma unroll
            for (int ks = 0; ks < 2; ks++) {
                bf16x8 pf = *reinterpret_cast<const bf16x8*>((char*)&plds[w][0] +
                    ((lr * 128 + ks * 64 + lg * 16) ^ ((lr & 7) << 4)));
#pragma unroll
                for (int nf2 = 0; nf2 < 8; nf2++) {
                    const int dh = nf2 * 16 + lr;
                    bf16x8 vf = *reinterpret_cast<const bf16x8*>(
                        vb + ((dh * 128 + ks * 64 + lg * 16) ^ VSWZ(dh)));
                    o[nf2] = __builtin_amdgcn_mfma_f32_16x16x32_bf16(pf, vf, o[nf2], 0, 0, 0);
                }
            }
            if (kt < last) STAGE_WRITE(cur ^ 1);
            __syncthreads();
            cur ^= 1;
        }
#pragma unroll
        for (int nf2 = 0; nf2 < 8; nf2++) {
            const int col = h * 128 + nf2 * 16 + lr;
#pragma unroll
            for (int q = 0; q < 4; q++) {
                const float v = o[nf2][q] / ls[q];
                out[(base + qr0 + q) * 2048 + col] = f2bf(v);
            }
        }
        __syncthreads();
    }
#undef STAGE_LOAD
#undef STAGE_WRITE
}

// ---------------- SwiGLU combine (one HFF quarter) ----------------
__global__ void swiglu_comb(const u16* __restrict__ f3, u16* __restrict__ comb) {
    const size_t u = (size_t)blockIdx.x * 256 + threadIdx.x;  // 8-elem units of [4096,2048]
    const size_t n = u >> 8;
    const int f = (int)(u & 255) << 3;
    const u16* gp = f3 + n * 6144 + f;
    union { uint4 q; u16 s[8]; } g, up, g2;
    g.q  = *reinterpret_cast<const uint4*>(gp);
    up.q = *reinterpret_cast<const uint4*>(gp + 2048);
    g2.q = *reinterpret_cast<const uint4*>(gp + 4096);
    u32 r[4];
#pragma unroll
    for (int i = 0; i < 4; i++) {
        float a0 = bf2f(g.s[2 * i]),     a1 = bf2f(g.s[2 * i + 1]);
        float b0 = bf2f(up.s[2 * i]),    b1 = bf2f(up.s[2 * i + 1]);
        float c0 = bf2f(g2.s[2 * i]),    c1 = bf2f(g2.s[2 * i + 1]);
        float r0 = a0 * sigm(a0) * b0 * sigm(c0);
        float r1 = a1 * sigm(a1) * b1 * sigm(c1);
        r[i] = (u32)f2bf(r0) | ((u32)f2bf(r1) << 16);
    }
    *reinterpret_cast<uint4*>(comb + n * 8192 + f) = make_uint4(r[0], r[1], r[2], r[3]);
}

// ---------------- launch ----------------
extern "C" void kernel_launch(void* const* d_in, const int* in_sizes, int n_in,
                              void* d_out, int out_size, void* d_ws, size_t ws_size,
                              hipStream_t stream) {
    const float* x      = (const float*)d_in[0];
    const float* q_w    = (const float*)d_in[1];
    const float* k_w    = (const float*)d_in[2];
    const float* v_w    = (const float*)d_in[3];
    const float* o_w    = (const float*)d_in[4];
    const float* temp   = (const float*)d_in[5];
    const float* ln1_w  = (const float*)d_in[6];
    const float* ln2_w  = (const float*)d_in[7];
    const float* gate_w = (const float*)d_in[8];
    const float* up_w   = (const float*)d_in[9];
    const float* gate2_w= (const float*)d_in[10];
    const float* down_w = (const float*)d_in[11];
    const float* ag_w   = (const float*)d_in[12];
    const float* ag_b   = (const float*)d_in[13];
    const float* fg_w   = (const float*)d_in[14];
    const float* fg_b   = (const float*)d_in[15];

    // ---- workspace regions (peak 251,658,240 B; lifetimes disjoint) ----
    char* ws = (char*)d_ws;
    u16*  Wbuf = (u16*)(ws);                      // 33,554,432 B  weight scratch (serial reuse)
    u16*  hbuf = (u16*)(ws + 33554432);           // 16,777,216 B  rmsnorm output
    float* x1  = (float*)(ws + 50331648);         // 33,554,432 B  post-attn residual (f32)
    u16*  combo= (u16*)(ws + 83886080);           // 67,108,864 B  [4096,8192] bf16
    char* E    = ws + 150994944;                  // 50,331,648 B  qkvact -> aof/aob -> ffn3q
    char* F    = ws + 201326592;                  // 33,554,432 B  attnb -> fff
    u16*  ffb  = (u16*)(ws + 234881024);          // 16,777,216 B

    u16*   qkvact = (u16*)E;                      // [4096,6144] bf16
    float* aof    = (float*)E;                    // [4096,2048] f32
    u16*   aob    = (u16*)(E + 33554432);         // [4096,2048] bf16
    u16*   ffn3q  = (u16*)E;                      // [4096,6144] bf16 (per quarter)
    u16*   attnb  = (u16*)F;                      // [4096,2048] bf16
    float* fff    = (float*)F;                    // [4096,2048] f32

    float* outp = (float*)d_out;
    const size_t DD = 2048ull * 2048ull;
    const int cg_d = (int)(DD / 4) / 256;         // 4096 blocks for a DxD weight

    // 1) h = rmsnorm(x, ln1)
    hipLaunchKernelGGL(rmsnorm_k, dim3(4096), dim3(256), 0, stream, x, ln1_w, hbuf);

    // 2) qkv = h @ [Wq;Wk;Wv]^T  (one GEMM, N=6144)
    hipLaunchKernelGGL(conv3_bf16, dim3(cg_d, 3), dim3(256), 0, stream,
                       q_w, k_w, v_w, Wbuf, Wbuf + DD, Wbuf + 2 * DD, (int)(DD / 4));
    hipLaunchKernelGGL((gemm_bt<0>), dim3(32 * 48), dim3(256), 0, stream,
                       hbuf, Wbuf, (float*)nullptr, qkvact,
                       (const float*)nullptr, (const float*)nullptr, (const float*)nullptr,
                       (float*)nullptr, 4096, 6144, 2048, 6144);

    // 3) l2-normalize q,k in place (q also scaled by temp[h])
    hipLaunchKernelGGL(qk_l2norm, dim3(32768), dim3(256), 0, stream, qkvact, temp);

    // 4) attention -> attnb
    hipLaunchKernelGGL(flash_attn, dim3(256), dim3(512), 0, stream, qkvact, attnb);

    // 5) attn_out = attn @ Wo^T
    hipLaunchKernelGGL(conv_bf16, dim3(cg_d), dim3(256), 0, stream, o_w, Wbuf, (int)(DD / 4));
    hipLaunchKernelGGL((gemm_bt<1>), dim3(32 * 16), dim3(256), 0, stream,
                       attnb, Wbuf, aof, aob,
                       (const float*)nullptr, (const float*)nullptr, (const float*)nullptr,
                       (float*)nullptr, 4096, 2048, 2048, 2048);

    // 6) x1 = sigmoid(attn_out@Wag^T + b)*attn_out + (1-g)*x
    hipLaunchKernelGGL(conv_bf16, dim3(cg_d), dim3(256), 0, stream, ag_w, Wbuf, (int)(DD / 4));
    hipLaunchKernelGGL((gemm_bt<2>), dim3(32 * 16), dim3(256), 0, stream,
                       aob, Wbuf, (float*)nullptr, (u16*)nullptr,
                       ag_b, aof, x, x1, 4096, 2048, 2048, 2048);

    // 7) h2 = rmsnorm(x1, ln2)
    hipLaunchKernelGGL(rmsnorm_k, dim3(4096), dim3(256), 0, stream, x1, ln2_w, hbuf);

    // 8) FFN in 4 HFF quarters
    for (int qd = 0; qd < 4; qd++) {
        const size_t wofs = (size_t)qd * 2048 * 2048;
        hipLaunchKernelGGL(conv3_bf16, dim3(cg_d, 3), dim3(256), 0, stream,
                           gate_w + wofs, up_w + wofs, gate2_w + wofs,
                           Wbuf, Wbuf + 2048 * 2048, Wbuf + 2ull * 2048 * 2048, (int)(DD / 4));
        hipLaunchKernelGGL((gemm_bt<0>), dim3(32 * 48), dim3(256), 0, stream,
                           hbuf, Wbuf, (float*)nullptr, ffn3q,
                           (const float*)nullptr, (const float*)nullptr, (const float*)nullptr,
                           (float*)nullptr, 4096, 6144, 2048, 6144);
        hipLaunchKernelGGL(swiglu_comb, dim3(4096), dim3(256), 0, stream, ffn3q, combo + qd * 2048);
    }

    // 9) ffn_out = combo @ Wdn^T
    hipLaunchKernelGGL(conv_bf16, dim3(16384), dim3(256), 0, stream, down_w, Wbuf, (int)(2048ull * 8192 / 4));
    hipLaunchKernelGGL((gemm_bt<1>), dim3(32 * 16), dim3(256), 0, stream,
                       combo, Wbuf, fff, ffb,
                       (const float*)nullptr, (const float*)nullptr, (const float*)nullptr,
                       (float*)nullptr, 4096, 2048, 8192, 2048);

    // 10) out = sigmoid(ffn_out@Wfg^T + b)*ffn_out + (1-g)*x1
    hipLaunchKernelGGL(conv_bf16, dim3(cg_d), dim3(256), 0, stream, fg_w, Wbuf, (int)(DD / 4));
    hipLaunchKernelGGL((gemm_bt<2>), dim3(32 * 16), dim3(256), 0, stream,
                       ffb, Wbuf, (float*)nullptr, (u16*)nullptr,
                       fg_b, fff, x1, outp, 4096, 2048, 2048, 2048);
}

// Round 6
// 1134.487 us; speedup vs baseline: 1.5153x; 1.1005x over previous
//
#include <hip/hip_runtime.h>

typedef unsigned short u16;
typedef unsigned int u32;
using bf16x8 = __attribute__((ext_vector_type(8))) short;
using f32x4  = __attribute__((ext_vector_type(4))) float;

#define EPS 1e-5f

__device__ __forceinline__ u16 f2bf(float f) {
    union { float f; u32 u; } v; v.f = f;
    u32 r = v.u + 0x7FFFu + ((v.u >> 16) & 1u);   // RNE
    return (u16)(r >> 16);
}
__device__ __forceinline__ float bf2f(u16 u) {
    union { u32 u; float f; } v; v.u = ((u32)u) << 16;
    return v.f;
}
__device__ __forceinline__ void gl16(const void* g, void* s) {
    __builtin_amdgcn_global_load_lds(
        (const __attribute__((address_space(1))) u32*)g,
        (__attribute__((address_space(3))) u32*)s, 16, 0, 0);
}
__device__ __forceinline__ float sigm(float x) { return 1.f / (1.f + __expf(-x)); }

// ---------------- fp32 -> bf16 convert ----------------
__global__ void conv_bf16(const float* __restrict__ src, u16* __restrict__ dst, int n4) {
    int i = blockIdx.x * 256 + threadIdx.x;
    if (i >= n4) return;
    float4 v = reinterpret_cast<const float4*>(src)[i];
    u32 lo = (u32)f2bf(v.x) | ((u32)f2bf(v.y) << 16);
    u32 hi = (u32)f2bf(v.z) | ((u32)f2bf(v.w) << 16);
    reinterpret_cast<uint2*>(dst)[i] = make_uint2(lo, hi);
}

__global__ void conv3_bf16(const float* __restrict__ s0, const float* __restrict__ s1,
                           const float* __restrict__ s2, u16* __restrict__ d0,
                           u16* __restrict__ d1, u16* __restrict__ d2, int n4) {
    int i = blockIdx.x * 256 + threadIdx.x;
    if (i >= n4) return;
    const float* src = (blockIdx.y == 0) ? s0 : (blockIdx.y == 1) ? s1 : s2;
    u16* dst = (blockIdx.y == 0) ? d0 : (blockIdx.y == 1) ? d1 : d2;
    float4 v = reinterpret_cast<const float4*>(src)[i];
    u32 lo = (u32)f2bf(v.x) | ((u32)f2bf(v.y) << 16);
    u32 hi = (u32)f2bf(v.z) | ((u32)f2bf(v.w) << 16);
    reinterpret_cast<uint2*>(dst)[i] = make_uint2(lo, hi);
}

// ---------------- RMSNorm: fp32 [4096,2048] -> bf16 ----------------
__global__ void rmsnorm_k(const float* __restrict__ x, const float* __restrict__ wt,
                          u16* __restrict__ out) {
    __shared__ float red[4];
    const int row = blockIdx.x, t = threadIdx.x;
    const float* xr = x + (size_t)row * 2048;
    float4 v0 = *reinterpret_cast<const float4*>(&xr[t * 8]);
    float4 v1 = *reinterpret_cast<const float4*>(&xr[t * 8 + 4]);
    float ss = v0.x*v0.x + v0.y*v0.y + v0.z*v0.z + v0.w*v0.w
             + v1.x*v1.x + v1.y*v1.y + v1.z*v1.z + v1.w*v1.w;
#pragma unroll
    for (int d = 1; d < 64; d <<= 1) ss += __shfl_xor(ss, d);
    if ((t & 63) == 0) red[t >> 6] = ss;
    __syncthreads();
    const float tot = red[0] + red[1] + red[2] + red[3];
    const float s = 1.f / sqrtf(tot * (1.f / 2048.f) + EPS);
    float4 w0 = *reinterpret_cast<const float4*>(&wt[t * 8]);
    float4 w1 = *reinterpret_cast<const float4*>(&wt[t * 8 + 4]);
    u32 o[4];
    o[0] = (u32)f2bf(v0.x * s * w0.x) | ((u32)f2bf(v0.y * s * w0.y) << 16);
    o[1] = (u32)f2bf(v0.z * s * w0.z) | ((u32)f2bf(v0.w * s * w0.w) << 16);
    o[2] = (u32)f2bf(v1.x * s * w1.x) | ((u32)f2bf(v1.y * s * w1.y) << 16);
    o[3] = (u32)f2bf(v1.z * s * w1.z) | ((u32)f2bf(v1.w * s * w1.w) << 16);
    *reinterpret_cast<uint4*>(&out[(size_t)row * 2048 + t * 8]) =
        make_uint4(o[0], o[1], o[2], o[3]);
}

// ---------------- L2 norm of q/k rows (in place); q scaled by temp[h] ----------------
__global__ void qk_l2norm(u16* __restrict__ qkv, const float* __restrict__ temp) {
    const int wid = blockIdx.x * 4 + (threadIdx.x >> 6);
    const int l = threadIdx.x & 63;
    const int n = wid >> 5;
    const int rem = wid & 31;
    const int which = rem >> 4;
    const int h = rem & 15;
    u16* p = qkv + (size_t)n * 6144 + which * 2048 + h * 128 + l * 2;
    u32 v = *reinterpret_cast<const u32*>(p);
    float f0 = bf2f((u16)(v & 0xffff)), f1 = bf2f((u16)(v >> 16));
    float ss = f0 * f0 + f1 * f1;
#pragma unroll
    for (int d = 1; d < 64; d <<= 1) ss += __shfl_xor(ss, d);
    float sc = 1.f / fmaxf(sqrtf(ss), 1e-12f);
    if (which == 0) sc *= temp[h];
    *reinterpret_cast<u32*>(p) = (u32)f2bf(f0 * sc) | ((u32)f2bf(f1 * sc) << 16);
}

// ---------------- NT GEMM, phase-pipelined: C[M,N] = A[M,K] x B[N,K]^T ----------------
// BM=128, BN=256, BK=64, 8 waves (2Mx4N), 3-buffer LDS ring (144KB dynamic),
// counted vmcnt(6), T2 swizzle, setprio around MFMA. Requires M%128==0, N%256==0, K%64==0.
template <int EPI>
__global__ __launch_bounds__(512, 1)
void gemm_bt(const u16* __restrict__ A, const u16* __restrict__ B,
             float* __restrict__ outF, u16* __restrict__ outB,
             const float* __restrict__ bias, const float* __restrict__ addend,
             const float* __restrict__ resid, float* __restrict__ outG,
             int M, int N, int K, int ldc) {
    extern __shared__ u16 lds[];   // 3 bufs x (A 8192 + B 16384) u16 = 147456 B
    const int nbn = N >> 8;
    const int nwg = (M >> 7) * nbn;
    const int orig = blockIdx.x;
    const int q8 = nwg >> 3, r8 = nwg & 7;
    const int xcd = orig & 7, lin = orig >> 3;
    const int wgid = (xcd < r8 ? xcd * (q8 + 1) : r8 * (q8 + 1) + (xcd - r8) * q8) + lin;
    const int g = wgid / (nbn << 3);
    const int rem = wgid - g * (nbn << 3);
    const int bn = rem >> 3;
    const int bm = (g << 3) + (rem & 7);

    const int t = threadIdx.x;
    const int w = t >> 6, l = t & 63;
    const int wr = w >> 2, wc = w & 3;       // 2M x 4N waves
    const int lr = l & 15, lg = l >> 4;
    const int NT = K >> 6;

    // staging: thread t covers granule (pr, ps); source column pre-swizzled (T2 both-sides)
    const int pr = t >> 3, ps = t & 7;
    const int sg = ps ^ (pr & 7);
    const u16* aSrc = A + (size_t)(bm * 128 + pr) * K + sg * 8;
    const u16* bSrc = B + (size_t)(bn * 256 + pr) * K + sg * 8;
    const size_t rowStep = (size_t)64 * K;

#define STAGE_P0(TT, bi) do {                                                   \
        u16* da = lds + (bi) * 24576 + t * 8;                                   \
        gl16(aSrc + (size_t)(TT) * 64, da);                                     \
        gl16(aSrc + rowStep + (size_t)(TT) * 64, da + 4096);                    \
        gl16(bSrc + (size_t)(TT) * 64, lds + (bi) * 24576 + 8192 + t * 8);      \
    } while (0)
#define STAGE_P1(TT, bi) do {                                                   \
        u16* db = lds + (bi) * 24576 + 8192 + t * 8;                            \
        gl16(bSrc + rowStep + (size_t)(TT) * 64, db + 4096);                    \
        gl16(bSrc + 2 * rowStep + (size_t)(TT) * 64, db + 8192);                \
        gl16(bSrc + 3 * rowStep + (size_t)(TT) * 64, db + 12288);               \
    } while (0)

    f32x4 acc[4][4];
#pragma unroll
    for (int i = 0; i < 4; i++)
#pragma unroll
        for (int j = 0; j < 4; j++) acc[i][j] = (f32x4){0.f, 0.f, 0.f, 0.f};

    // read-side swizzled k-offsets (bytes): ((ks*4+lg)<<4) ^ ((lr&7)<<4)
    const int xr = (lr & 7) << 4;
    const int kof0 = ((lg) << 4) ^ xr;          // ks=0
    const int kof1 = ((4 + lg) << 4) ^ xr;      // ks=1

    // prologue: stage K-tiles 0 and 1
    STAGE_P0(0, 0); STAGE_P1(0, 0);
    if (NT > 1) {
        STAGE_P0(1, 1); STAGE_P1(1, 1);
        asm volatile("s_waitcnt vmcnt(6)" ::: "memory");
    } else {
        asm volatile("s_waitcnt vmcnt(0)" ::: "memory");
    }
    __builtin_amdgcn_s_barrier();

    for (int T = 0; T < NT; ++T) {
        const int bi = T % 3;
        const int sbi = (T + 2) % 3;
        const bool st = (T + 2) < NT;
        const char* bufA = (const char*)(lds + bi * 24576);
        const char* bufB = bufA + 16384;
        // ---- phase 0: read all B frags + A m-frags 0,1; stage A+B0 of T+2 ----
        bf16x8 bf[4][2], af[2][2];
#pragma unroll
        for (int n = 0; n < 4; n++) {
            const int rb = wc * 64 + n * 16 + lr;
            bf[n][0] = *reinterpret_cast<const bf16x8*>(bufB + rb * 128 + kof0);
            bf[n][1] = *reinterpret_cast<const bf16x8*>(bufB + rb * 128 + kof1);
        }
#pragma unroll
        for (int m = 0; m < 2; m++) {
            const int ra = wr * 64 + m * 16 + lr;
            af[m][0] = *reinterpret_cast<const bf16x8*>(bufA + ra * 128 + kof0);
            af[m][1] = *reinterpret_cast<const bf16x8*>(bufA + ra * 128 + kof1);
        }
        if (st) STAGE_P0(T + 2, sbi);
        __builtin_amdgcn_s_barrier();
        __builtin_amdgcn_s_setprio(1);
#pragma unroll
        for (int m = 0; m < 2; m++)
#pragma unroll
            for (int n = 0; n < 4; n++) {
                acc[m][n] = __builtin_amdgcn_mfma_f32_16x16x32_bf16(af[m][0], bf[n][0], acc[m][n], 0, 0, 0);
                acc[m][n] = __builtin_amdgcn_mfma_f32_16x16x32_bf16(af[m][1], bf[n][1], acc[m][n], 0, 0, 0);
            }
        __builtin_amdgcn_s_setprio(0);
        __builtin_amdgcn_s_barrier();
        // ---- phase 1: read A m-frags 2,3; stage B1..B3 of T+2 ----
        bf16x8 ag[2][2];
#pragma unroll
        for (int m = 0; m < 2; m++) {
            const int ra = wr * 64 + (m + 2) * 16 + lr;
            ag[m][0] = *reinterpret_cast<const bf16x8*>(bufA + ra * 128 + kof0);
            ag[m][1] = *reinterpret_cast<const bf16x8*>(bufA + ra * 128 + kof1);
        }
        if (st) STAGE_P1(T + 2, sbi);
        __builtin_amdgcn_s_barrier();
        __builtin_amdgcn_s_setprio(1);
#pragma unroll
        for (int m = 0; m < 2; m++)
#pragma unroll
            for (int n = 0; n < 4; n++) {
                acc[m + 2][n] = __builtin_amdgcn_mfma_f32_16x16x32_bf16(ag[m][0], bf[n][0], acc[m + 2][n], 0, 0, 0);
                acc[m + 2][n] = __builtin_amdgcn_mfma_f32_16x16x32_bf16(ag[m][1], bf[n][1], acc[m + 2][n], 0, 0, 0);
            }
        __builtin_amdgcn_s_setprio(0);
        // ---- end of K-tile: counted drain (never 0 in steady state) ----
        if (st) {
            asm volatile("s_waitcnt vmcnt(6)" ::: "memory");
        } else if (T + 1 < NT) {
            asm volatile("s_waitcnt vmcnt(0)" ::: "memory");
        }
        __builtin_amdgcn_s_barrier();
    }
#undef STAGE_P0
#undef STAGE_P1

    // ---- epilogue ----
#pragma unroll
    for (int m = 0; m < 4; m++) {
        const int row = bm * 128 + wr * 64 + m * 16 + lg * 4;
#pragma unroll
        for (int n = 0; n < 4; n++) {
            const int col = bn * 256 + wc * 64 + n * 16 + lr;
#pragma unroll
            for (int q = 0; q < 4; q++) {
                const size_t idx = (size_t)(row + q) * ldc + col;
                const float v = acc[m][n][q];
                if (EPI == 0) {
                    outB[idx] = f2bf(v);
                } else if (EPI == 1) {
                    outF[idx] = v;
                    outB[idx] = f2bf(v);
                } else {
                    const float g2 = sigm(v + bias[col]);
                    outG[idx] = g2 * addend[idx] + (1.f - g2) * resid[idx];
                }
            }
        }
    }
}

// ---------------- causal flash attention (QBLK=128, 8 waves, reg-staged dbuf) ----------------
#define VSWZ(dh) (((((dh) >> 3) ^ (dh)) & 7) << 4)
__global__ __launch_bounds__(512) void flash_attn(const u16* __restrict__ qkv,
                                                  u16* __restrict__ out) {
    __shared__ u16 klds[2][64 * 128];
    __shared__ u16 vlds[2][128 * 64];
    __shared__ u16 plds[8][16 * 64];
    const int t = threadIdx.x, w = t >> 6, l = t & 63;
    const int lr = l & 15, lg = l >> 4;
    const int b0 = blockIdx.x;
    const int xcd = b0 & 7, i0 = b0 >> 3;
    const int bh = ((i0 & 3) << 3) | xcd;
    const int p = i0 >> 2;
    const int b = bh >> 4, h = bh & 15;
    const size_t base = (size_t)b * 2048;
    const int sr0 = t >> 4;
    const int sc0 = (t & 15) << 3;

    uint4 kreg0, kreg1, vreg0, vreg1;

#define STAGE_LOAD(KT) do {                                                          \
        const size_t gg = (base + (size_t)(KT) * 64 + sr0) * 6144 + h * 128 + sc0;   \
        kreg0 = *reinterpret_cast<const uint4*>(&qkv[gg + 2048]);                    \
        vreg0 = *reinterpret_cast<const uint4*>(&qkv[gg + 4096]);                    \
        kreg1 = *reinterpret_cast<const uint4*>(&qkv[gg + 32 * 6144 + 2048]);        \
        vreg1 = *reinterpret_cast<const uint4*>(&qkv[gg + 32 * 6144 + 4096]);        \
    } while (0)

#define STAGE_WRITE(BUF) do {                                                                     \
        char* kb = (char*)&klds[BUF][0];                                                          \
        char* vb = (char*)&vlds[BUF][0];                                                          \
        *reinterpret_cast<uint4*>(kb + ((sr0 * 256 + sc0 * 2) ^ ((sr0 & 7) << 4))) = kreg0;       \
        *reinterpret_cast<uint4*>(kb + (((sr0 + 32) * 256 + sc0 * 2) ^ ((sr0 & 7) << 4))) = kreg1;\
        union { uint4 u; u16 s[8]; } vv;                                                          \
        vv.u = vreg0;                                                                             \
        _Pragma("unroll")                                                                         \
        for (int jj = 0; jj < 8; jj++) {                                                          \
            const int dh = sc0 + jj;                                                              \
            *reinterpret_cast<u16*>(vb + ((dh * 128 + sr0 * 2) ^ VSWZ(dh))) = vv.s[jj];           \
        }                                                                                         \
        vv.u = vreg1;                                                                             \
        _Pragma("unroll")                                                                         \
        for (int jj = 0; jj < 8; jj++) {                                                          \
            const int dh = sc0 + jj;                                                              \
            *reinterpret_cast<u16*>(vb + ((dh * 128 + (sr0 + 32) * 2) ^ VSWZ(dh))) = vv.s[jj];    \
        }                                                                                         \
    } while (0)

    for (int phase = 0; phase < 2; ++phase) {
        const int qt = phase ? (15 - p) : p;
        const int last = 2 * qt + 1;
        const int qrow = qt * 128 + w * 16 + lr;
        const int qr0 = qt * 128 + w * 16 + lg * 4;
        bf16x8 qf[4];
#pragma unroll
        for (int kk = 0; kk < 4; kk++)
            qf[kk] = *reinterpret_cast<const bf16x8*>(
                &qkv[(base + qrow) * 6144 + h * 128 + kk * 32 + lg * 8]);
        f32x4 o[8];
#pragma unroll
        for (int i = 0; i < 8; i++) o[i] = (f32x4){0.f, 0.f, 0.f, 0.f};
        float m[4] = {-1e30f, -1e30f, -1e30f, -1e30f};
        float ls[4] = {0.f, 0.f, 0.f, 0.f};

        STAGE_LOAD(0);
        int cur = 0;
        STAGE_WRITE(0);
        __syncthreads();

        for (int kt = 0; kt <= last; ++kt) {
            if (kt < last) STAGE_LOAD(kt + 1);
            const char* kb = (const char*)&klds[cur][0];
            const char* vb = (const char*)&vlds[cur][0];
            f32x4 s[4];
#pragma unroll
            for (int nf = 0; nf < 4; nf++) {
                f32x4 a = (f32x4){0.f, 0.f, 0.f, 0.f};
                const int kv = nf * 16 + lr;
#pragma unroll
                for (int kk = 0; kk < 4; kk++) {
                    bf16x8 kf = *reinterpret_cast<const bf16x8*>(
                        kb + ((kv * 256 + kk * 64 + lg * 16) ^ ((kv & 7) << 4)));
                    a = __builtin_amdgcn_mfma_f32_16x16x32_bf16(qf[kk], kf, a, 0, 0, 0);
                }
                s[nf] = a;
            }
            if (kt >= 2 * qt) {
#pragma unroll
                for (int nf = 0; nf < 4; nf++) {
                    const int kvi = kt * 64 + nf * 16 + lr;
#pragma unroll
                    for (int q = 0; q < 4; q++)
                        if (kvi > qr0 + q) s[nf][q] = -1e30f;
                }
            }
            float mx[4] = {-1e30f, -1e30f, -1e30f, -1e30f};
#pragma unroll
            for (int nf = 0; nf < 4; nf++)
#pragma unroll
                for (int q = 0; q < 4; q++) mx[q] = fmaxf(mx[q], s[nf][q]);
#pragma unroll
            for (int q = 0; q < 4; q++) {
#pragma unroll
                for (int d = 1; d < 16; d <<= 1) mx[q] = fmaxf(mx[q], __shfl_xor(mx[q], d));
            }
            float fac[4], rs[4];
#pragma unroll
            for (int q = 0; q < 4; q++) {
                const float mn = fmaxf(m[q], mx[q]);
                fac[q] = __expf(m[q] - mn);
                m[q] = mn;
                rs[q] = 0.f;
            }
#pragma unroll
            for (int nf = 0; nf < 4; nf++) {
#pragma unroll
                for (int q = 0; q < 4; q++) {
                    const float pv = __expf(s[nf][q] - m[q]);
                    s[nf][q] = pv;
                    rs[q] += pv;
                }
            }
#pragma unroll
            for (int nf = 0; nf < 4; nf++) {
                const int col = nf * 16 + lr;
#pragma unroll
                for (int q = 0; q < 4; q++) {
                    const int row = lg * 4 + q;
                    *reinterpret_cast<u16*>((char*)&plds[w][0] +
                        ((row * 128 + col * 2) ^ ((row & 7) << 4))) = f2bf(s[nf][q]);
                }
            }
#pragma unroll
            for (int q = 0; q < 4; q++) {
#pragma unroll
                for (int d = 1; d < 16; d <<= 1) rs[q] += __shfl_xor(rs[q], d);
                ls[q] = ls[q] * fac[q] + rs[q];
            }
#pragma unroll
            for (int nf2 = 0; nf2 < 8; nf2++)
#pragma unroll
                for (int q = 0; q < 4; q++) o[nf2][q] *= fac[q];
#pragma unroll
            for (int ks = 0; ks < 2; ks++) {
                bf16x8 pf = *reinterpret_cast<const bf16x8*>((char*)&plds[w][0] +
                    ((lr * 128 + ks * 64 + lg * 16) ^ ((lr & 7) << 4)));
#pragma unroll
                for (int nf2 = 0; nf2 < 8; nf2++) {
                    const int dh = nf2 * 16 + lr;
                    bf16x8 vf = *reinterpret_cast<const bf16x8*>(
                        vb + ((dh * 128 + ks * 64 + lg * 16) ^ VSWZ(dh)));
                    o[nf2] = __builtin_amdgcn_mfma_f32_16x16x32_bf16(pf, vf, o[nf2], 0, 0, 0);
                }
            }
            if (kt < last) STAGE_WRITE(cur ^ 1);
            __syncthreads();
            cur ^= 1;
        }
#pragma unroll
        for (int nf2 = 0; nf2 < 8; nf2++) {
            const int col = h * 128 + nf2 * 16 + lr;
#pragma unroll
            for (int q = 0; q < 4; q++) {
                const float v = o[nf2][q] / ls[q];
                out[(base + qr0 + q) * 2048 + col] = f2bf(v);
            }
        }
        __syncthreads();
    }
#undef STAGE_LOAD
#undef STAGE_WRITE
}

// ---------------- SwiGLU combine (one HFF quarter) ----------------
__global__ void swiglu_comb(const u16* __restrict__ f3, u16* __restrict__ comb) {
    const size_t u = (size_t)blockIdx.x * 256 + threadIdx.x;
    const size_t n = u >> 8;
    const int f = (int)(u & 255) << 3;
    const u16* gp = f3 + n * 6144 + f;
    union { uint4 q; u16 s[8]; } g, up, g2;
    g.q  = *reinterpret_cast<const uint4*>(gp);
    up.q = *reinterpret_cast<const uint4*>(gp + 2048);
    g2.q = *reinterpret_cast<const uint4*>(gp + 4096);
    u32 r[4];
#pragma unroll
    for (int i = 0; i < 4; i++) {
        float a0 = bf2f(g.s[2 * i]),     a1 = bf2f(g.s[2 * i + 1]);
        float b0 = bf2f(up.s[2 * i]),    b1 = bf2f(up.s[2 * i + 1]);
        float c0 = bf2f(g2.s[2 * i]),    c1 = bf2f(g2.s[2 * i + 1]);
        float r0 = a0 * sigm(a0) * b0 * sigm(c0);
        float r1 = a1 * sigm(a1) * b1 * sigm(c1);
        r[i] = (u32)f2bf(r0) | ((u32)f2bf(r1) << 16);
    }
    *reinterpret_cast<uint4*>(comb + n * 8192 + f) = make_uint4(r[0], r[1], r[2], r[3]);
}

// ---------------- launch ----------------
extern "C" void kernel_launch(void* const* d_in, const int* in_sizes, int n_in,
                              void* d_out, int out_size, void* d_ws, size_t ws_size,
                              hipStream_t stream) {
    const float* x      = (const float*)d_in[0];
    const float* q_w    = (const float*)d_in[1];
    const float* k_w    = (const float*)d_in[2];
    const float* v_w    = (const float*)d_in[3];
    const float* o_w    = (const float*)d_in[4];
    const float* temp   = (const float*)d_in[5];
    const float* ln1_w  = (const float*)d_in[6];
    const float* ln2_w  = (const float*)d_in[7];
    const float* gate_w = (const float*)d_in[8];
    const float* up_w   = (const float*)d_in[9];
    const float* gate2_w= (const float*)d_in[10];
    const float* down_w = (const float*)d_in[11];
    const float* ag_w   = (const float*)d_in[12];
    const float* ag_b   = (const float*)d_in[13];
    const float* fg_w   = (const float*)d_in[14];
    const float* fg_b   = (const float*)d_in[15];

    // allow 144KB dynamic LDS for the GEMM instantiations (idempotent)
    const int GEMM_LDS = 147456;
    (void)hipFuncSetAttribute(reinterpret_cast<const void*>(&gemm_bt<0>),
                              hipFuncAttributeMaxDynamicSharedMemorySize, GEMM_LDS);
    (void)hipFuncSetAttribute(reinterpret_cast<const void*>(&gemm_bt<1>),
                              hipFuncAttributeMaxDynamicSharedMemorySize, GEMM_LDS);
    (void)hipFuncSetAttribute(reinterpret_cast<const void*>(&gemm_bt<2>),
                              hipFuncAttributeMaxDynamicSharedMemorySize, GEMM_LDS);

    // ---- workspace regions (peak 251,658,240 B; lifetimes disjoint) ----
    char* ws = (char*)d_ws;
    u16*  Wbuf = (u16*)(ws);                      // 33,554,432 B  weight scratch
    u16*  hbuf = (u16*)(ws + 33554432);           // 16,777,216 B
    float* x1  = (float*)(ws + 50331648);         // 33,554,432 B
    u16*  combo= (u16*)(ws + 83886080);           // 67,108,864 B
    char* E    = ws + 150994944;                  // 50,331,648 B
    char* F    = ws + 201326592;                  // 33,554,432 B
    u16*  ffb  = (u16*)(ws + 234881024);          // 16,777,216 B

    u16*   qkvact = (u16*)E;
    float* aof    = (float*)E;
    u16*   aob    = (u16*)(E + 33554432);
    u16*   ffn3q  = (u16*)E;
    u16*   attnb  = (u16*)F;
    float* fff    = (float*)F;

    float* outp = (float*)d_out;
    const size_t DD = 2048ull * 2048ull;
    const int cg_d = (int)(DD / 4) / 256;
    const int GRID_BIG = 32 * 24;   // M=4096,N=6144
    const int GRID_SM  = 32 * 8;    // M=4096,N=2048

    // 1) h = rmsnorm(x, ln1)
    hipLaunchKernelGGL(rmsnorm_k, dim3(4096), dim3(256), 0, stream, x, ln1_w, hbuf);

    // 2) qkv = h @ [Wq;Wk;Wv]^T
    hipLaunchKernelGGL(conv3_bf16, dim3(cg_d, 3), dim3(256), 0, stream,
                       q_w, k_w, v_w, Wbuf, Wbuf + DD, Wbuf + 2 * DD, (int)(DD / 4));
    hipLaunchKernelGGL((gemm_bt<0>), dim3(GRID_BIG), dim3(512), GEMM_LDS, stream,
                       hbuf, Wbuf, (float*)nullptr, qkvact,
                       (const float*)nullptr, (const float*)nullptr, (const float*)nullptr,
                       (float*)nullptr, 4096, 6144, 2048, 6144);

    // 3) l2-normalize q,k (q scaled by temp)
    hipLaunchKernelGGL(qk_l2norm, dim3(32768), dim3(256), 0, stream, qkvact, temp);

    // 4) attention
    hipLaunchKernelGGL(flash_attn, dim3(256), dim3(512), 0, stream, qkvact, attnb);

    // 5) attn_out = attn @ Wo^T
    hipLaunchKernelGGL(conv_bf16, dim3(cg_d), dim3(256), 0, stream, o_w, Wbuf, (int)(DD / 4));
    hipLaunchKernelGGL((gemm_bt<1>), dim3(GRID_SM), dim3(512), GEMM_LDS, stream,
                       attnb, Wbuf, aof, aob,
                       (const float*)nullptr, (const float*)nullptr, (const float*)nullptr,
                       (float*)nullptr, 4096, 2048, 2048, 2048);

    // 6) x1 = sigmoid(attn_out@Wag^T + b)*attn_out + (1-g)*x
    hipLaunchKernelGGL(conv_bf16, dim3(cg_d), dim3(256), 0, stream, ag_w, Wbuf, (int)(DD / 4));
    hipLaunchKernelGGL((gemm_bt<2>), dim3(GRID_SM), dim3(512), GEMM_LDS, stream,
                       aob, Wbuf, (float*)nullptr, (u16*)nullptr,
                       ag_b, aof, x, x1, 4096, 2048, 2048, 2048);

    // 7) h2 = rmsnorm(x1, ln2)
    hipLaunchKernelGGL(rmsnorm_k, dim3(4096), dim3(256), 0, stream, x1, ln2_w, hbuf);

    // 8) FFN in 4 HFF quarters
    for (int qd = 0; qd < 4; qd++) {
        const size_t wofs = (size_t)qd * 2048 * 2048;
        hipLaunchKernelGGL(conv3_bf16, dim3(cg_d, 3), dim3(256), 0, stream,
                           gate_w + wofs, up_w + wofs, gate2_w + wofs,
                           Wbuf, Wbuf + 2048 * 2048, Wbuf + 2ull * 2048 * 2048, (int)(DD / 4));
        hipLaunchKernelGGL((gemm_bt<0>), dim3(GRID_BIG), dim3(512), GEMM_LDS, stream,
                           hbuf, Wbuf, (float*)nullptr, ffn3q,
                           (const float*)nullptr, (const float*)nullptr, (const float*)nullptr,
                           (float*)nullptr, 4096, 6144, 2048, 6144);
        hipLaunchKernelGGL(swiglu_comb, dim3(4096), dim3(256), 0, stream, ffn3q, combo + qd * 2048);
    }

    // 9) ffn_out = combo @ Wdn^T
    hipLaunchKernelGGL(conv_bf16, dim3(16384), dim3(256), 0, stream, down_w, Wbuf, (int)(2048ull * 8192 / 4));
    hipLaunchKernelGGL((gemm_bt<1>), dim3(GRID_SM), dim3(512), GEMM_LDS, stream,
                       combo, Wbuf, fff, ffb,
                       (const float*)nullptr, (const float*)nullptr, (const float*)nullptr,
                       (float*)nullptr, 4096, 2048, 8192, 2048);

    // 10) out = sigmoid(ffn_out@Wfg^T + b)*ffn_out + (1-g)*x1
    hipLaunchKernelGGL(conv_bf16, dim3(cg_d), dim3(256), 0, stream, fg_w, Wbuf, (int)(DD / 4));
    hipLaunchKernelGGL((gemm_bt<2>), dim3(GRID_SM), dim3(512), GEMM_LDS, stream,
                       ffb, Wbuf, (float*)nullptr, (u16*)nullptr,
                       fg_b, fff, x1, outp, 4096, 2048, 2048, 2048);
}